// Round 8
// baseline (2891.210 us; speedup 1.0000x reference)
//
#include <hip/hip_runtime.h>
#include <hip/hip_bf16.h>

#define BB 64
#define LL 196
#define ENC 2048
#define DEC 512
#define EMB 512
#define ATT 512
#define VV 20000
#define TT 26
#define TM1 25

typedef __attribute__((ext_vector_type(8))) short bf16x8;
typedef __attribute__((ext_vector_type(4))) short bf16x4;
typedef __attribute__((ext_vector_type(4))) float f32x4;

#define MFMA16(a,b,c) __builtin_amdgcn_mfma_f32_16x16x32_bf16(a,b,c,0,0,0)

typedef const __attribute__((address_space(1))) void g_void;
typedef __attribute__((address_space(3))) void l_void;

// async global->LDS, 16B per lane; dest is wave-uniform base + lane*16
__device__ __forceinline__ void stage16(const void* g, void* l){
    __builtin_amdgcn_global_load_lds((g_void*)g, (l_void*)l, 16, 0, 0);
}

#define WAITV(N) asm volatile("s_waitcnt vmcnt(" #N ")" ::: "memory")
#define PHASE_SYNC() do { __builtin_amdgcn_s_barrier(); __builtin_amdgcn_sched_barrier(0); } while(0)

__device__ __forceinline__ float tanh_fast(float x){
    float ax = fabsf(x);
    float e  = __expf(-2.f*ax);
    float r  = (1.f - e)/(1.f + e);
    return x >= 0.f ? r : -r;
}
__device__ __forceinline__ float sigmoidf_(float x){
    return 1.f/(1.f + __expf(-x));
}
__device__ __forceinline__ short f2bf(float v){
    __hip_bfloat16 b = __float2bfloat16(v);
    return __builtin_bit_cast(short, b);
}
__device__ __forceinline__ float bf2f(short s){
    __hip_bfloat16 b = __builtin_bit_cast(__hip_bfloat16, s);
    return __bfloat162float(b);
}

// ---------------------------------------------------------------------------
// sort + cap/lens outputs + bias_sum
// ---------------------------------------------------------------------------
__global__ void k_sort(const int* __restrict__ clen, const int* __restrict__ cap,
                       const float* __restrict__ bih, const float* __restrict__ bhh,
                       int* __restrict__ sind, int* __restrict__ lens_s,
                       float* __restrict__ bsum,
                       float* __restrict__ out_cap, float* __restrict__ out_lens)
{
    int i = threadIdx.x;
    int li = clen[i];
    int r = 0;
    for (int j = 0; j < BB; j++){
        int lj = clen[j];
        r += (lj > li) || (lj == li && j < i);
    }
    sind[r] = i;
    lens_s[r] = li - 1;
    out_lens[r] = (float)(li - 1);
    for (int t = 0; t < TT; t++)
        out_cap[r*TT + t] = (float)cap[i*TT + t];
    for (int j = i; j < 4*DEC; j += BB)
        bsum[j] = bih[j] + bhh[j];
}

// ---------------------------------------------------------------------------
// k_prep: packs / conversions / mean / embedding (Wd/Wfb packs removed —
// the merged attnz GEMV reads the original fp32 weights directly)
// ---------------------------------------------------------------------------
struct PrepArgs {
    const float* enc; const int* sind; short* enc_s;
    const float* Wfc; short* Wfcb;
    const float* Wih; const float* Whh; short* Bg;
    const float* We;  short* Web;
    float* mean;
    const float* embW; const int* cap; short* embs;
    int fast; int blkoff;
};

#define SEG0 12544               // cvt_enc
#define SEG1 (SEG0 + 5000)       // Wfc pack
#define SEG2 (SEG1 + 2560)       // Wih pack
#define SEG3 (SEG2 + 512)        // We pack
#define SEG4 (SEG3 + 512)        // Whh pack
#define SEG5 (SEG4 + 512)        // mean
#define SEG6 (SEG5 + 1600)       // emb

__device__ __forceinline__ void pack_frag(int idx, const float* src, int ld,
                                          int K, int N, short* dst,
                                          int ktOff, int ntOff, int ntTot, bool NK)
{
    int ntCnt = N >> 4, ktCnt = K >> 5;
    int lane = idx & 63, rest = idx >> 6;
    if (rest >= ktCnt*ntCnt) return;
    int nt = rest % ntCnt, kt = rest / ntCnt;
    int k = kt*32 + (lane>>4)*8, n = nt*16 + (lane&15);
    bf16x8 v;
    #pragma unroll
    for (int j = 0; j < 8; j++){
        float f = NK ? src[(size_t)n*ld + k + j] : src[(size_t)(k+j)*ld + n];
        v[j] = f2bf(f);
    }
    *(bf16x8*)(dst + ((size_t)((kt+ktOff)*ntTot + (nt+ntOff))*64 + lane)*8) = v;
}

__launch_bounds__(256)
__global__ void k_prep(PrepArgs P)
{
    int blk = blockIdx.x + P.blkoff, tid = threadIdx.x;
    if (blk < SEG0){
        if (!P.fast) return;
        size_t idx = ((size_t)blk*256 + tid)*8;
        int r = (int)(idx / (LL*ENC));
        size_t rem = idx - (size_t)r*(LL*ENC);
        const float* s = P.enc + (size_t)P.sind[r]*(LL*ENC) + rem;
        bf16x8 v;
        float4 f0 = *(const float4*)s, f1 = *(const float4*)(s+4);
        v[0]=f2bf(f0.x); v[1]=f2bf(f0.y); v[2]=f2bf(f0.z); v[3]=f2bf(f0.w);
        v[4]=f2bf(f1.x); v[5]=f2bf(f1.y); v[6]=f2bf(f1.z); v[7]=f2bf(f1.w);
        *(bf16x8*)(P.enc_s + idx) = v;
    } else if (blk < SEG1){
        pack_frag((blk-SEG0)*256 + tid, P.Wfc, VV, 512, VV, P.Wfcb, 0, 0, 1250, false);
    } else if (blk < SEG2){
        pack_frag((blk-SEG1)*256 + tid, P.Wih, 2560, 2560, 2048, P.Bg, 0, 0, 128, true);
    } else if (blk < SEG3){
        pack_frag((blk-SEG2)*256 + tid, P.We, ATT, ENC, ATT, P.Web, 0, 0, 32, false);
    } else if (blk < SEG4){
        pack_frag((blk-SEG3)*256 + tid, P.Whh, 512, 512, 2048, P.Bg, 80, 0, 128, true);
    } else if (blk < SEG5){
        int rel = blk - SEG4;           // 0..511
        int b = rel >> 3;
        int e = (rel & 7)*256 + tid;
        int sb = P.sind[b];
        const float* p = P.enc + ((size_t)sb*LL)*ENC + e;
        float s = 0.f;
        for (int l = 0; l < LL; l++) s += p[(size_t)l*ENC];
        P.mean[b*ENC + e] = s * (1.f/(float)LL);
    } else if (blk < SEG6){
        int rel = blk - SEG5;           // (b, t)
        int b = rel / 25, t = rel % 25;
        int token = P.cap[P.sind[b]*TT + t];
        const float* src = P.embW + (size_t)token*EMB + tid*2;
        unsigned u = (unsigned)(unsigned short)f2bf(src[0]) |
                     ((unsigned)(unsigned short)f2bf(src[1]) << 16);
        ((unsigned*)(P.embs + ((size_t)b*TM1 + t)*EMB))[tid] = u;
    }
}

// ---------------------------------------------------------------------------
// h0/c0 split-K fp32
// ---------------------------------------------------------------------------
#define KT 32
__launch_bounds__(256)
__global__ void k_h0part(const float* __restrict__ A1, const float* __restrict__ B1,
                         const float* __restrict__ B2, float* __restrict__ hpart)
{
    __shared__ float As[KT][64];
    __shared__ float Bs[KT][64];
    const int tid = threadIdx.x;
    const int n0  = blockIdx.x*64;
    const int kq  = blockIdx.y;
    float acc[4][4] = {};
    const int lrow = tid >> 3, lcol = tid & 7;
    const int bn = (tid & 15)*4, bk = tid >> 4;
    const int bi0 = (tid >> 4)*4, nj0 = (tid & 15)*4;
    for (int k0 = kq*256; k0 < kq*256 + 256; k0 += KT){
        #pragma unroll
        for (int p = 0; p < 2; p++){
            int m = lrow + p*32;
            float4 v = *(const float4*)(A1 + (size_t)m*2048 + k0 + lcol*4);
            As[lcol*4+0][m] = v.x; As[lcol*4+1][m] = v.y;
            As[lcol*4+2][m] = v.z; As[lcol*4+3][m] = v.w;
        }
        {
            bool hi = (n0 >= 512);
            const float* B = hi ? B2 : B1;
            int ncol = n0 - (hi ? 512 : 0) + bn;
            #pragma unroll
            for (int p = 0; p < 2; p++){
                int k = bk + p*16;
                *(float4*)&Bs[k][bn] = *(const float4*)(B + (size_t)(k0+k)*512 + ncol);
            }
        }
        __syncthreads();
        #pragma unroll
        for (int k = 0; k < KT; k++){
            const float4 av = *(const float4*)&As[k][bi0];
            const float4 bv = *(const float4*)&Bs[k][nj0];
            acc[0][0] += av.x*bv.x; acc[0][1] += av.x*bv.y; acc[0][2] += av.x*bv.z; acc[0][3] += av.x*bv.w;
            acc[1][0] += av.y*bv.x; acc[1][1] += av.y*bv.y; acc[1][2] += av.y*bv.z; acc[1][3] += av.y*bv.w;
            acc[2][0] += av.z*bv.x; acc[2][1] += av.z*bv.y; acc[2][2] += av.z*bv.z; acc[2][3] += av.z*bv.w;
            acc[3][0] += av.w*bv.x; acc[3][1] += av.w*bv.y; acc[3][2] += av.w*bv.z; acc[3][3] += av.w*bv.w;
        }
        __syncthreads();
    }
    #pragma unroll
    for (int i = 0; i < 4; i++)
        #pragma unroll
        for (int j = 0; j < 4; j++){
            int b = bi0 + i, n = n0 + nj0 + j;
            hpart[((size_t)kq*64 + b)*1024 + n] = acc[i][j];
        }
}

__global__ void k_h0fin(const float* __restrict__ hpart, const float* __restrict__ bh0,
                        const float* __restrict__ bc0, short* __restrict__ h0,
                        float* __restrict__ c)
{
    int idx = blockIdx.x*256 + threadIdx.x;
    int b = idx >> 10, n = idx & 1023;
    float v = (n < 512) ? bh0[n] : bc0[n-512];
    for (int kq = 0; kq < 8; kq++) v += hpart[((size_t)kq*64 + b)*1024 + n];
    float r = tanh_fast(v);
    if (n < 512) h0[b*512 + n] = f2bf(r);
    else         c[b*512 + (n-512)] = r;
}

// ---------------------------------------------------------------------------
// enc_att MFMA: grid (196,4), 2 nt per wave
// ---------------------------------------------------------------------------
template<bool BF16SRC>
__launch_bounds__(256)
__global__ void k_encatt_mfma(const void* __restrict__ encp, const int* __restrict__ sind,
                              const short* __restrict__ Web, const float* __restrict__ be,
                              short* __restrict__ enc_att)
{
    __shared__ short As[64*32];
    int tid = threadIdx.x, wv = tid>>6, lane = tid&63;
    int hi = lane>>4, lo = lane&15;
    int m0 = blockIdx.x*64;
    int ntbase = blockIdx.y*8 + wv*2;
    int srow = tid>>2, schunk = tid&3;
    const short* gsrcB = nullptr; const float* gsrcF = nullptr;
    if (BF16SRC){
        gsrcB = (const short*)encp + (size_t)(m0+srow)*ENC + schunk*8;
    } else {
        int grow = m0 + srow;
        int b = grow/LL, l = grow - b*LL;
        gsrcF = (const float*)encp + ((size_t)sind[b]*LL + l)*ENC + schunk*8;
    }
    int sws = srow*32 + (schunk ^ ((srow>>1)&3))*8;
    f32x4 acc[2][4] = {};
    for (int kt = 0; kt < 64; kt++){
        bf16x8 v;
        if (BF16SRC){
            v = *(const bf16x8*)(gsrcB + kt*32);
        } else {
            float4 f0 = *(const float4*)(gsrcF + kt*32);
            float4 f1 = *(const float4*)(gsrcF + kt*32 + 4);
            v[0]=f2bf(f0.x); v[1]=f2bf(f0.y); v[2]=f2bf(f0.z); v[3]=f2bf(f0.w);
            v[4]=f2bf(f1.x); v[5]=f2bf(f1.y); v[6]=f2bf(f1.z); v[7]=f2bf(f1.w);
        }
        __syncthreads();
        *(bf16x8*)(As + sws) = v;
        __syncthreads();
        bf16x8 af[4];
        #pragma unroll
        for (int m = 0; m < 4; m++){
            int r = m*16 + lo;
            af[m] = *(const bf16x8*)(As + r*32 + (hi ^ ((r>>1)&3))*8);
        }
        #pragma unroll
        for (int n = 0; n < 2; n++){
            bf16x8 b = *(const bf16x8*)(Web + ((size_t)(kt*32 + ntbase + n)*64 + lane)*8);
            #pragma unroll
            for (int m = 0; m < 4; m++)
                acc[n][m] = MFMA16(af[m], b, acc[n][m]);
        }
    }
    #pragma unroll
    for (int n = 0; n < 2; n++)
        #pragma unroll
        for (int m = 0; m < 4; m++)
            #pragma unroll
            for (int j = 0; j < 4; j++){
                int row = m0 + m*16 + hi*4 + j;
                int col = (ntbase + n)*16 + lo;
                enc_att[(size_t)row*ATT + col] = f2bf(acc[n][m][j] + be[col]);
            }
}

// ---------------------------------------------------------------------------
// K2': MERGED dec_att GEMV + Wfb-gate GEMV + scores/softmax/z/inp.
// One block per b, 512 thr. Row-local: block b needs only h[b,:].
// Weights read as ORIGINAL fp32 (Wd 1MB + Wfb 4MB, L2-resident per XCD).
// ---------------------------------------------------------------------------
__launch_bounds__(512)
__global__ void k_attnz2(const short* __restrict__ h_in,
                         const float* __restrict__ Wd, const float* __restrict__ bd,
                         const float* __restrict__ Wfb, const float* __restrict__ bfb,
                         const short* __restrict__ encat,
                         const float* __restrict__ Wa, const float* __restrict__ ba,
                         const short* __restrict__ embs,
                         const short* __restrict__ enc_s, const float* __restrict__ enc,
                         const int* __restrict__ sind, const int* __restrict__ lens_s,
                         short* __restrict__ inp, float* __restrict__ out_alphas,
                         int t, int fast)
{
    __shared__ float hf[512];
    __shared__ float da[512];
    __shared__ float was[512];
    __shared__ float sc[200];
    __shared__ float red[16];
    __shared__ float al[200];
    __shared__ float zpart[4*2048];
    int b = blockIdx.x, tid = threadIdx.x;
    int lane = tid & 63, wv = tid >> 6;

    hf[tid] = bf2f(h_in[b*512 + tid]);
    was[tid] = Wa[tid];
    if (tid < 256){
        const unsigned* s32 = (const unsigned*)(embs + ((size_t)b*TM1 + t)*EMB);
        ((unsigned*)(inp + (size_t)b*2560))[tid] = s32[tid];
    }
    __syncthreads();

    // ---- dg GEMV: col n = tid, coalesced dword streams, 4 partial chains ----
    {
        const float* Wcol = Wd + tid;
        float a0 = 0.f, a1 = 0.f, a2 = 0.f, a3 = 0.f;
        for (int k = 0; k < 512; k += 4){
            float4 h4 = *(const float4*)&hf[k];
            a0 += h4.x * Wcol[(size_t)(k+0)*ATT];
            a1 += h4.y * Wcol[(size_t)(k+1)*ATT];
            a2 += h4.z * Wcol[(size_t)(k+2)*ATT];
            a3 += h4.w * Wcol[(size_t)(k+3)*ATT];
        }
        da[tid] = (a0 + a1) + (a2 + a3) + bd[tid];
    }
    __syncthreads();

    // ---- scores ----
    float ba_v = ba[0];
    for (int l = wv; l < LL; l += 8){
        const short* ea = encat + ((size_t)b*LL + l)*ATT;
        float s = 0.f;
        #pragma unroll
        for (int q = 0; q < 8; q++){
            int a = lane + q*64;
            s += tanh_fast(bf2f(ea[a]) + da[a]) * was[a];
        }
        #pragma unroll
        for (int off = 32; off; off >>= 1) s += __shfl_xor(s, off);
        if (lane == 0) sc[l] = s + ba_v;
    }
    __syncthreads();
    float v = -1e30f, e = 0.f;
    if (tid < 256){
        v = (tid < LL) ? sc[tid] : -1e30f;
        float mx = v;
        #pragma unroll
        for (int off = 32; off; off >>= 1) mx = fmaxf(mx, __shfl_xor(mx, off));
        if (lane == 0) red[wv] = mx;
    }
    __syncthreads();
    float mxa = fmaxf(fmaxf(red[0], red[1]), fmaxf(red[2], red[3]));
    if (tid < 256){
        e = (tid < LL) ? __expf(v - mxa) : 0.f;
        float sm = e;
        #pragma unroll
        for (int off = 32; off; off >>= 1) sm += __shfl_xor(sm, off);
        if (lane == 0) red[8 + wv] = sm;
    }
    __syncthreads();
    float tot = red[8] + red[9] + red[10] + red[11];
    if (tid < LL){
        float alv = e / tot;
        al[tid] = alv;
        float m = (t < lens_s[b]) ? 1.f : 0.f;
        out_alphas[((size_t)b*TM1 + t)*LL + tid] = alv * m;
    }

    // ---- gate GEMV (independent of softmax): 4 cols/thread, float4 streams,
    // result kept in registers; mapping matches the final combine (c0=4*tid) ----
    float g4[4];
    {
        int c0 = tid*4;
        const float* Wg = Wfb + c0;
        float4 acc0 = {0.f,0.f,0.f,0.f}, acc1 = {0.f,0.f,0.f,0.f};
        for (int k = 0; k < 512; k += 2){
            float4 w0 = *(const float4*)&Wg[(size_t)(k+0)*ENC];
            float4 w1 = *(const float4*)&Wg[(size_t)(k+1)*ENC];
            float hv0 = hf[k], hv1 = hf[k+1];
            acc0.x += hv0*w0.x; acc0.y += hv0*w0.y; acc0.z += hv0*w0.z; acc0.w += hv0*w0.w;
            acc1.x += hv1*w1.x; acc1.y += hv1*w1.y; acc1.z += hv1*w1.z; acc1.w += hv1*w1.w;
        }
        g4[0] = sigmoidf_(acc0.x + acc1.x + bfb[c0+0]);
        g4[1] = sigmoidf_(acc0.y + acc1.y + bfb[c0+1]);
        g4[2] = sigmoidf_(acc0.z + acc1.z + bfb[c0+2]);
        g4[3] = sigmoidf_(acc0.w + acc1.w + bfb[c0+3]);
    }
    __syncthreads();

    // ---- z: thread (ls, cs): ls = l-slice 0..3 (49 iters), cs = 16-col group ----
    {
        int ls = tid >> 7;          // 0..3
        int cs = tid & 127;         // 0..127
        int c0 = cs*16;
        float a16[16] = {};
        if (fast){
            const short* base = enc_s + ((size_t)b*LL)*ENC + c0;
            for (int l = ls; l < LL; l += 4){
                float av = al[l];
                const short* r = base + (size_t)l*ENC;
                bf16x8 v0 = *(const bf16x8*)(r);
                bf16x8 v1 = *(const bf16x8*)(r + 8);
                #pragma unroll
                for (int j = 0; j < 8; j++){
                    a16[j]     += av*bf2f(v0[j]);
                    a16[8 + j] += av*bf2f(v1[j]);
                }
            }
        } else {
            const float* base = enc + ((size_t)sind[b]*LL)*ENC + c0;
            for (int l = ls; l < LL; l += 4){
                float av = al[l];
                const float* r = base + (size_t)l*ENC;
                float4 f0 = *(const float4*)(r),     f1 = *(const float4*)(r+4);
                float4 f2 = *(const float4*)(r + 8), f3 = *(const float4*)(r+12);
                a16[0]+=av*f0.x; a16[1]+=av*f0.y; a16[2]+=av*f0.z; a16[3]+=av*f0.w;
                a16[4]+=av*f1.x; a16[5]+=av*f1.y; a16[6]+=av*f1.z; a16[7]+=av*f1.w;
                a16[8]+=av*f2.x; a16[9]+=av*f2.y; a16[10]+=av*f2.z; a16[11]+=av*f2.w;
                a16[12]+=av*f3.x; a16[13]+=av*f3.y; a16[14]+=av*f3.z; a16[15]+=av*f3.w;
            }
        }
        // rotated-order scalar writes: instruction jj writes slot (jj+cs)&15
        float* zp = zpart + ls*2048 + c0;
        #pragma unroll
        for (int jj = 0; jj < 16; jj++){
            int slot = (jj + cs) & 15;
            zp[slot] = a16[slot];
        }
    }
    __syncthreads();
    {
        int c = tid*4;
        bf16x4 o;
        #pragma unroll
        for (int j = 0; j < 4; j++){
            float s = zpart[0*2048 + c + j] + zpart[1*2048 + c + j]
                    + zpart[2*2048 + c + j] + zpart[3*2048 + c + j];
            o[j] = f2bf(g4[j] * s);
        }
        *(bf16x4*)(inp + (size_t)b*2560 + 512 + c) = o;
    }
}

// ---------------------------------------------------------------------------
// K3: g GEMM (split-K=2) + LSTM. 32 blocks x 512 thr.
// 3 kt per phase: 16 phases. Ring DEPTH 3 x 48KB = 144KB LDS.
// ---------------------------------------------------------------------------
__launch_bounds__(512)
__global__ void k_glstm(const short* __restrict__ inp, const short* __restrict__ h_in,
                        const short* __restrict__ Bg, const float* __restrict__ bsum,
                        float* __restrict__ c, short* __restrict__ h_out)
{
    __shared__ short ring[3*24576];           // 144KB; gs unioned in after loop
    float* gs = (float*)ring;
    int tid = threadIdx.x, wv = tid>>6, lane = tid&63;
    int hi = lane>>4, lo = lane&15;
    int gate = wv & 3, khalf = wv >> 2;
    int j16 = blockIdx.x;
    int nt = gate*32 + j16;
    int sl   = tid >> 8;             // A-slice group (khalf) this thread stages
    int st   = tid & 255;
    int srow = st >> 2;
    int swc  = (st&3) ^ ((srow>>1)&3);
    int swz  = (hi ^ ((lo>>1)&3))*8;
    auto STG = [&](int q){
        short* buf = ring + (q%3)*24576;
        #pragma unroll
        for (int j = 0; j < 3; j++){
            int kt = sl*48 + 3*q + j;
            const short* src;
            if (kt < 80) src = inp  + (size_t)srow*2560 + kt*32 + swc*8;
            else         src = h_in + (size_t)srow*512  + (kt-80)*32 + swc*8;
            stage16(src, buf + (sl*3 + j)*2048 + (wv&3)*512);
            int ktw = khalf*48 + 3*q + j;
            stage16(Bg + ((size_t)(ktw*128 + nt)*64 + lane)*8,
                    buf + 12288 + wv*1536 + j*512);
        }
    };
    STG(0); STG(1);
    f32x4 acc[4] = {};
    auto CMP = [&](int pp){
        const short* buf = ring + (pp%3)*24576;
        #pragma unroll
        for (int j = 0; j < 3; j++){
            bf16x8 b = *(const bf16x8*)(buf + 12288 + wv*1536 + j*512 + lane*8);
            const short* Ab = buf + (khalf*3 + j)*2048;
            #pragma unroll
            for (int m = 0; m < 4; m++){
                bf16x8 a = *(const bf16x8*)(Ab + (m*16 + lo)*32 + swz);
                acc[m] = MFMA16(a, b, acc[m]);
            }
        }
    };
    for (int pp = 0; pp < 14; pp++){
        WAITV(6); PHASE_SYNC();
        STG(pp + 2);
        CMP(pp);
    }
    WAITV(6); PHASE_SYNC(); CMP(14);
    WAITV(0); PHASE_SYNC(); CMP(15);
    __syncthreads();                 // all ring reads done before gs overwrite
    #pragma unroll
    for (int m = 0; m < 4; m++)
        #pragma unroll
        for (int j = 0; j < 4; j++)
            gs[wv*1088 + (m*16 + hi*4 + j)*17 + lo] = acc[m][j];
    __syncthreads();
    #pragma unroll
    for (int rep = 0; rep < 2; rep++){
        int idx = rep*512 + tid;
        int row = idx >> 4, cl = idx & 15;
        int col = j16*16 + cl;
        float s0 = gs[0*1088 + row*17 + cl] + gs[4*1088 + row*17 + cl] + bsum[col];
        float s1 = gs[1*1088 + row*17 + cl] + gs[5*1088 + row*17 + cl] + bsum[512 + col];
        float s2 = gs[2*1088 + row*17 + cl] + gs[6*1088 + row*17 + cl] + bsum[1024 + col];
        float s3 = gs[3*1088 + row*17 + cl] + gs[7*1088 + row*17 + cl] + bsum[1536 + col];
        int ci = row*512 + col;
        float cn = sigmoidf_(s1)*c[ci] + sigmoidf_(s0)*tanh_fast(s2);
        c[ci] = cn;
        h_out[ci] = f2bf(sigmoidf_(s3)*tanh_fast(cn));
    }
}

// ---------------------------------------------------------------------------
// K4: batched pred GEMM over all 25 steps. grid (313,5). Tail-race fixed.
// ---------------------------------------------------------------------------
__launch_bounds__(256)
__global__ void k_predall(const short* __restrict__ hh, const short* __restrict__ Wfcb,
                          const float* __restrict__ bfc, const int* __restrict__ lens_s,
                          float* __restrict__ out_preds)
{
    __shared__ short ring[4*2048];
    int tid = threadIdx.x, wv = tid>>6, lane = tid&63;
    int hi = lane>>4, lo = lane&15;
    int nt = blockIdx.x*4 + wv;
    if (nt > 1249) nt = 1249;        // duplicate work; identical values stored
    int mt0 = blockIdx.y*5;
    bf16x8 breg[16];
    #pragma unroll
    for (int kt = 0; kt < 16; kt++)
        breg[kt] = *(const bf16x8*)(Wfcb + ((size_t)(kt*1250 + nt)*64 + lane)*8);
    int col = nt*16 + lo;
    float bv = bfc[col];
    int lv[16];
    #pragma unroll
    for (int m = 0; m < 4; m++)
        #pragma unroll
        for (int j = 0; j < 4; j++)
            lv[m*4 + j] = lens_s[m*16 + hi*4 + j];

    int srow = tid>>2;
    int swc  = (tid&3) ^ ((srow>>1)&3);
    int swz  = (hi ^ ((lo>>1)&3))*8;
    const short* hh0 = hh + (size_t)(mt0 + 1)*(BB*DEC);
    auto STG = [&](int q){
        const short* src = hh0 + (size_t)(q>>4)*(BB*DEC) + (size_t)srow*512
                         + (q&15)*32 + swc*8;
        stage16(src, ring + (q&3)*2048 + wv*512);
    };
    STG(0); STG(1); STG(2);

    auto CMP = [&](f32x4* acc, int kt, int pp){
        const short* base = ring + (pp&3)*2048;
        #pragma unroll
        for (int m = 0; m < 4; m++){
            bf16x8 a = *(const bf16x8*)(base + (m*16 + lo)*32 + swz);
            acc[m] = MFMA16(a, breg[kt], acc[m]);
        }
    };
    auto STORE = [&](f32x4* acc, int mta){
        #pragma unroll
        for (int m = 0; m < 4; m++)
            #pragma unroll
            for (int j = 0; j < 4; j++){
                int row = m*16 + hi*4 + j;
                float mk = (mta < lv[m*4 + j]) ? 1.f : 0.f;
                out_preds[((size_t)row*TM1 + mta)*VV + col] = mk*(acc[m][j] + bv);
            }
    };

    for (int mt = 0; mt < 4; mt++){
        f32x4 acc[4] = {};
        #pragma unroll
        for (int kt = 0; kt < 16; kt++){
            int pp = mt*16 + kt;
            WAITV(2); PHASE_SYNC();
            STG(pp + 3);
            CMP(acc, kt, pp);
        }
        STORE(acc, mt0 + mt);
    }
    {   // mt = 4 with counted tail drain
        f32x4 acc[4] = {};
        #pragma unroll
        for (int kt = 0; kt < 13; kt++){
            int pp = 64 + kt;
            WAITV(2); PHASE_SYNC();
            if (pp < 77) STG(pp + 3);
            CMP(acc, kt, pp);
        }
        WAITV(2); PHASE_SYNC(); CMP(acc, 13, 77);
        WAITV(1); PHASE_SYNC(); CMP(acc, 14, 78);
        WAITV(0); PHASE_SYNC(); CMP(acc, 15, 79);
        STORE(acc, mt0 + 4);
    }
}

// ---------------------------------------------------------------------------
extern "C" void kernel_launch(void* const* d_in, const int* in_sizes, int n_in,
                              void* d_out, int out_size, void* d_ws, size_t ws_size,
                              hipStream_t stream)
{
    const float* enc  = (const float*)d_in[0];
    const int*   cap  = (const int*)  d_in[1];
    const int*   clen = (const int*)  d_in[2];
    const float* embW = (const float*)d_in[3];
    const float* We   = (const float*)d_in[4];
    const float* be   = (const float*)d_in[5];
    const float* Wd   = (const float*)d_in[6];
    const float* bd   = (const float*)d_in[7];
    const float* Wa   = (const float*)d_in[8];
    const float* ba   = (const float*)d_in[9];
    const float* Wih  = (const float*)d_in[10];
    const float* bih  = (const float*)d_in[11];
    const float* Whh  = (const float*)d_in[12];
    const float* bhh  = (const float*)d_in[13];
    const float* Wfb  = (const float*)d_in[14];
    const float* bfb  = (const float*)d_in[15];
    const float* Wh0  = (const float*)d_in[16];
    const float* bh0  = (const float*)d_in[17];
    const float* Wc0  = (const float*)d_in[18];
    const float* bc0  = (const float*)d_in[19];
    const float* Wfc  = (const float*)d_in[20];
    const float* bfc  = (const float*)d_in[21];

    char* w = (char*)d_ws;
    size_t cur = 0;
    auto alloc = [&](size_t bytes)->char*{
        char* p = w + cur; cur = (cur + bytes + 255) & ~(size_t)255; return p;
    };
    int*   sind   = (int*)  alloc(256);
    int*   lens_s = (int*)  alloc(256);
    float* bsum   = (float*)alloc(4*DEC*4);
    float* mean   = (float*)alloc(BB*ENC*4);
    float* hpart  = (float*)alloc((size_t)8*64*1024*4);
    float* c      = (float*)alloc(BB*DEC*4);
    short* hh     = (short*)alloc((size_t)(TM1+1)*BB*DEC*2);
    short* inp    = (short*)alloc(BB*2560*2);
    short* embs   = (short*)alloc((size_t)BB*TM1*EMB*2);
    short* Web    = (short*)alloc((size_t)ENC*ATT*2);
    short* Bg     = (short*)alloc((size_t)3072*2048*2);
    short* Wfcb   = (short*)alloc((size_t)512*VV*2);
    short* encat  = (short*)alloc((size_t)BB*LL*ATT*2);
    short* enc_s  = (short*)alloc((size_t)BB*LL*ENC*2);
    bool fast = (ws_size >= cur);
    int fastI = fast ? 1 : 0;

    float* out        = (float*)d_out;
    float* out_preds  = out;
    float* out_alphas = out + 32000000ull;
    float* out_cap    = out + 32313600ull;
    float* out_lens   = out + 32315264ull;

    // ---- prologue ----
    k_sort<<<1, 64, 0, stream>>>(clen, cap, bih, bhh, sind, lens_s, bsum,
                                 out_cap, out_lens);
    PrepArgs P;
    P.enc = enc; P.sind = sind; P.enc_s = enc_s;
    P.Wfc = Wfc; P.Wfcb = Wfcb;
    P.Wih = Wih; P.Whh = Whh; P.Bg = Bg;
    P.We = We; P.Web = Web;
    P.mean = mean;
    P.embW = embW; P.cap = cap; P.embs = embs;
    P.fast = fastI;
    P.blkoff = 0;
    k_prep<<<SEG0, 256, 0, stream>>>(P);          // enc conversion half
    PrepArgs P2 = P;
    P2.blkoff = SEG0;
    k_prep<<<SEG6 - SEG0, 256, 0, stream>>>(P2);  // weight-pack half

    k_h0part<<<dim3(16, 8), 256, 0, stream>>>(mean, Wh0, Wc0, hpart);
    k_h0fin<<<256, 256, 0, stream>>>(hpart, bh0, bc0, hh, c);

    if (fast)
        k_encatt_mfma<true ><<<dim3(196, 4), 256, 0, stream>>>(enc_s, sind, Web, be, encat);
    else
        k_encatt_mfma<false><<<dim3(196, 4), 256, 0, stream>>>(enc,   sind, Web, be, encat);

    // ---- decode loop: 2 dispatches per step ----
    for (int t = 0; t < TM1; t++){
        const short* h_in  = hh + (size_t)t*(BB*DEC);
        short*       h_out = hh + (size_t)(t+1)*(BB*DEC);
        k_attnz2<<<64, 512, 0, stream>>>(h_in, Wd, bd, Wfb, bfb, encat, Wa, ba,
                                         embs, enc_s, enc, sind, lens_s,
                                         inp, out_alphas, t, fastI);
        k_glstm<<<32, 512, 0, stream>>>(inp, h_in, Bg, bsum, c, h_out);
    }
    // ---- batched pred GEMM over all steps ----
    k_predall<<<dim3(313, 5), 256, 0, stream>>>(hh, Wfcb, bfc, lens_s, out_preds);
}

// Round 9
// 1875.701 us; speedup vs baseline: 1.5414x; 1.5414x over previous
//
#include <hip/hip_runtime.h>
#include <hip/hip_bf16.h>

#define BB 64
#define LL 196
#define ENC 2048
#define DEC 512
#define EMB 512
#define ATT 512
#define VV 20000
#define TT 26
#define TM1 25

typedef __attribute__((ext_vector_type(8))) short bf16x8;
typedef __attribute__((ext_vector_type(4))) short bf16x4;
typedef __attribute__((ext_vector_type(4))) float f32x4;

#define MFMA16(a,b,c) __builtin_amdgcn_mfma_f32_16x16x32_bf16(a,b,c,0,0,0)

typedef const __attribute__((address_space(1))) void g_void;
typedef __attribute__((address_space(3))) void l_void;

// async global->LDS, 16B per lane; dest is wave-uniform base + lane*16
__device__ __forceinline__ void stage16(const void* g, void* l){
    __builtin_amdgcn_global_load_lds((g_void*)g, (l_void*)l, 16, 0, 0);
}

#define WAITV(N) asm volatile("s_waitcnt vmcnt(" #N ")" ::: "memory")
#define PHASE_SYNC() do { __builtin_amdgcn_s_barrier(); __builtin_amdgcn_sched_barrier(0); } while(0)

__device__ __forceinline__ float tanh_fast(float x){
    float ax = fabsf(x);
    float e  = __expf(-2.f*ax);
    float r  = (1.f - e)/(1.f + e);
    return x >= 0.f ? r : -r;
}
__device__ __forceinline__ float sigmoidf_(float x){
    return 1.f/(1.f + __expf(-x));
}
__device__ __forceinline__ short f2bf(float v){
    __hip_bfloat16 b = __float2bfloat16(v);
    return __builtin_bit_cast(short, b);
}
__device__ __forceinline__ float bf2f(short s){
    __hip_bfloat16 b = __builtin_bit_cast(__hip_bfloat16, s);
    return __bfloat162float(b);
}

// ---------------------------------------------------------------------------
// sort + cap/lens outputs + bias_sum
// ---------------------------------------------------------------------------
__global__ void k_sort(const int* __restrict__ clen, const int* __restrict__ cap,
                       const float* __restrict__ bih, const float* __restrict__ bhh,
                       int* __restrict__ sind, int* __restrict__ lens_s,
                       float* __restrict__ bsum,
                       float* __restrict__ out_cap, float* __restrict__ out_lens)
{
    int i = threadIdx.x;
    int li = clen[i];
    int r = 0;
    for (int j = 0; j < BB; j++){
        int lj = clen[j];
        r += (lj > li) || (lj == li && j < i);
    }
    sind[r] = i;
    lens_s[r] = li - 1;
    out_lens[r] = (float)(li - 1);
    for (int t = 0; t < TT; t++)
        out_cap[r*TT + t] = (float)cap[i*TT + t];
    for (int j = i; j < 4*DEC; j += BB)
        bsum[j] = bih[j] + bhh[j];
}

// ---------------------------------------------------------------------------
// k_prep: all packs / conversions / mean / embedding (segmented, 2 launches)
// ---------------------------------------------------------------------------
struct PrepArgs {
    const float* enc; const int* sind; short* enc_s;
    const float* Wfc; short* Wfcb;
    const float* Wih; const float* Whh; short* Bg;
    const float* We;  short* Web;
    const float* Wfb; short* Bfb;
    const float* Wd;  short* Wdp;
    float* mean;
    const float* embW; const int* cap; short* embs;
    int fast; int blkoff;
};

#define SEG0 12544               // cvt_enc
#define SEG1 (SEG0 + 5000)       // Wfc pack
#define SEG2 (SEG1 + 2560)       // Wih pack
#define SEG3 (SEG2 + 512)        // We pack
#define SEG4 (SEG3 + 512)        // Wfb pack
#define SEG5 (SEG4 + 512)        // Whh pack
#define SEG6 (SEG5 + 512)        // mean
#define SEG7 (SEG6 + 1600)       // emb
#define SEG8 (SEG7 + 128)        // Wd pack

__device__ __forceinline__ void pack_frag(int idx, const float* src, int ld,
                                          int K, int N, short* dst,
                                          int ktOff, int ntOff, int ntTot, bool NK)
{
    int ntCnt = N >> 4, ktCnt = K >> 5;
    int lane = idx & 63, rest = idx >> 6;
    if (rest >= ktCnt*ntCnt) return;
    int nt = rest % ntCnt, kt = rest / ntCnt;
    int k = kt*32 + (lane>>4)*8, n = nt*16 + (lane&15);
    bf16x8 v;
    #pragma unroll
    for (int j = 0; j < 8; j++){
        float f = NK ? src[(size_t)n*ld + k + j] : src[(size_t)(k+j)*ld + n];
        v[j] = f2bf(f);
    }
    *(bf16x8*)(dst + ((size_t)((kt+ktOff)*ntTot + (nt+ntOff))*64 + lane)*8) = v;
}

__launch_bounds__(256)
__global__ void k_prep(PrepArgs P)
{
    int blk = blockIdx.x + P.blkoff, tid = threadIdx.x;
    if (blk < SEG0){
        if (!P.fast) return;
        size_t idx = ((size_t)blk*256 + tid)*8;
        int r = (int)(idx / (LL*ENC));
        size_t rem = idx - (size_t)r*(LL*ENC);
        const float* s = P.enc + (size_t)P.sind[r]*(LL*ENC) + rem;
        bf16x8 v;
        float4 f0 = *(const float4*)s, f1 = *(const float4*)(s+4);
        v[0]=f2bf(f0.x); v[1]=f2bf(f0.y); v[2]=f2bf(f0.z); v[3]=f2bf(f0.w);
        v[4]=f2bf(f1.x); v[5]=f2bf(f1.y); v[6]=f2bf(f1.z); v[7]=f2bf(f1.w);
        *(bf16x8*)(P.enc_s + idx) = v;
    } else if (blk < SEG1){
        pack_frag((blk-SEG0)*256 + tid, P.Wfc, VV, 512, VV, P.Wfcb, 0, 0, 1250, false);
    } else if (blk < SEG2){
        pack_frag((blk-SEG1)*256 + tid, P.Wih, 2560, 2560, 2048, P.Bg, 0, 0, 128, true);
    } else if (blk < SEG3){
        pack_frag((blk-SEG2)*256 + tid, P.We, ATT, ENC, ATT, P.Web, 0, 0, 32, false);
    } else if (blk < SEG4){
        pack_frag((blk-SEG3)*256 + tid, P.Wfb, ENC, 512, 2048, P.Bfb, 0, 0, 128, false);
    } else if (blk < SEG5){
        pack_frag((blk-SEG4)*256 + tid, P.Whh, 512, 512, 2048, P.Bg, 80, 0, 128, true);
    } else if (blk < SEG6){
        int rel = blk - SEG5;           // 0..511
        int b = rel >> 3;
        int e = (rel & 7)*256 + tid;
        int sb = P.sind[b];
        const float* p = P.enc + ((size_t)sb*LL)*ENC + e;
        float s = 0.f;
        for (int l = 0; l < LL; l++) s += p[(size_t)l*ENC];
        P.mean[b*ENC + e] = s * (1.f/(float)LL);
    } else if (blk < SEG7){
        int rel = blk - SEG6;           // (b, t)
        int b = rel / 25, t = rel % 25;
        int token = P.cap[P.sind[b]*TT + t];
        const float* src = P.embW + (size_t)token*EMB + tid*2;
        unsigned u = (unsigned)(unsigned short)f2bf(src[0]) |
                     ((unsigned)(unsigned short)f2bf(src[1]) << 16);
        ((unsigned*)(P.embs + ((size_t)b*TM1 + t)*EMB))[tid] = u;
    } else if (blk < SEG8){
        pack_frag((blk-SEG7)*256 + tid, P.Wd, ATT, 512, 512, P.Wdp, 0, 0, 32, false);
    }
}

// ---------------------------------------------------------------------------
// h0/c0 split-K fp32
// ---------------------------------------------------------------------------
#define KT 32
__launch_bounds__(256)
__global__ void k_h0part(const float* __restrict__ A1, const float* __restrict__ B1,
                         const float* __restrict__ B2, float* __restrict__ hpart)
{
    __shared__ float As[KT][64];
    __shared__ float Bs[KT][64];
    const int tid = threadIdx.x;
    const int n0  = blockIdx.x*64;
    const int kq  = blockIdx.y;
    float acc[4][4] = {};
    const int lrow = tid >> 3, lcol = tid & 7;
    const int bn = (tid & 15)*4, bk = tid >> 4;
    const int bi0 = (tid >> 4)*4, nj0 = (tid & 15)*4;
    for (int k0 = kq*256; k0 < kq*256 + 256; k0 += KT){
        #pragma unroll
        for (int p = 0; p < 2; p++){
            int m = lrow + p*32;
            float4 v = *(const float4*)(A1 + (size_t)m*2048 + k0 + lcol*4);
            As[lcol*4+0][m] = v.x; As[lcol*4+1][m] = v.y;
            As[lcol*4+2][m] = v.z; As[lcol*4+3][m] = v.w;
        }
        {
            bool hi = (n0 >= 512);
            const float* B = hi ? B2 : B1;
            int ncol = n0 - (hi ? 512 : 0) + bn;
            #pragma unroll
            for (int p = 0; p < 2; p++){
                int k = bk + p*16;
                *(float4*)&Bs[k][bn] = *(const float4*)(B + (size_t)(k0+k)*512 + ncol);
            }
        }
        __syncthreads();
        #pragma unroll
        for (int k = 0; k < KT; k++){
            const float4 av = *(const float4*)&As[k][bi0];
            const float4 bv = *(const float4*)&Bs[k][nj0];
            acc[0][0] += av.x*bv.x; acc[0][1] += av.x*bv.y; acc[0][2] += av.x*bv.z; acc[0][3] += av.x*bv.w;
            acc[1][0] += av.y*bv.x; acc[1][1] += av.y*bv.y; acc[1][2] += av.y*bv.z; acc[1][3] += av.y*bv.w;
            acc[2][0] += av.z*bv.x; acc[2][1] += av.z*bv.y; acc[2][2] += av.z*bv.z; acc[2][3] += av.z*bv.w;
            acc[3][0] += av.w*bv.x; acc[3][1] += av.w*bv.y; acc[3][2] += av.w*bv.z; acc[3][3] += av.w*bv.w;
        }
        __syncthreads();
    }
    #pragma unroll
    for (int i = 0; i < 4; i++)
        #pragma unroll
        for (int j = 0; j < 4; j++){
            int b = bi0 + i, n = n0 + nj0 + j;
            hpart[((size_t)kq*64 + b)*1024 + n] = acc[i][j];
        }
}

__global__ void k_h0fin(const float* __restrict__ hpart, const float* __restrict__ bh0,
                        const float* __restrict__ bc0, short* __restrict__ h0,
                        float* __restrict__ c)
{
    int idx = blockIdx.x*256 + threadIdx.x;
    int b = idx >> 10, n = idx & 1023;
    float v = (n < 512) ? bh0[n] : bc0[n-512];
    for (int kq = 0; kq < 8; kq++) v += hpart[((size_t)kq*64 + b)*1024 + n];
    float r = tanh_fast(v);
    if (n < 512) h0[b*512 + n] = f2bf(r);
    else         c[b*512 + (n-512)] = r;
}

// ---------------------------------------------------------------------------
// enc_att MFMA: grid (196,4), 2 nt per wave
// ---------------------------------------------------------------------------
template<bool BF16SRC>
__launch_bounds__(256)
__global__ void k_encatt_mfma(const void* __restrict__ encp, const int* __restrict__ sind,
                              const short* __restrict__ Web, const float* __restrict__ be,
                              short* __restrict__ enc_att)
{
    __shared__ short As[64*32];
    int tid = threadIdx.x, wv = tid>>6, lane = tid&63;
    int hi = lane>>4, lo = lane&15;
    int m0 = blockIdx.x*64;
    int ntbase = blockIdx.y*8 + wv*2;
    int srow = tid>>2, schunk = tid&3;
    const short* gsrcB = nullptr; const float* gsrcF = nullptr;
    if (BF16SRC){
        gsrcB = (const short*)encp + (size_t)(m0+srow)*ENC + schunk*8;
    } else {
        int grow = m0 + srow;
        int b = grow/LL, l = grow - b*LL;
        gsrcF = (const float*)encp + ((size_t)sind[b]*LL + l)*ENC + schunk*8;
    }
    int sws = srow*32 + (schunk ^ ((srow>>1)&3))*8;
    f32x4 acc[2][4] = {};
    for (int kt = 0; kt < 64; kt++){
        bf16x8 v;
        if (BF16SRC){
            v = *(const bf16x8*)(gsrcB + kt*32);
        } else {
            float4 f0 = *(const float4*)(gsrcF + kt*32);
            float4 f1 = *(const float4*)(gsrcF + kt*32 + 4);
            v[0]=f2bf(f0.x); v[1]=f2bf(f0.y); v[2]=f2bf(f0.z); v[3]=f2bf(f0.w);
            v[4]=f2bf(f1.x); v[5]=f2bf(f1.y); v[6]=f2bf(f1.z); v[7]=f2bf(f1.w);
        }
        __syncthreads();
        *(bf16x8*)(As + sws) = v;
        __syncthreads();
        bf16x8 af[4];
        #pragma unroll
        for (int m = 0; m < 4; m++){
            int r = m*16 + lo;
            af[m] = *(const bf16x8*)(As + r*32 + (hi ^ ((r>>1)&3))*8);
        }
        #pragma unroll
        for (int n = 0; n < 2; n++){
            bf16x8 b = *(const bf16x8*)(Web + ((size_t)(kt*32 + ntbase + n)*64 + lane)*8);
            #pragma unroll
            for (int m = 0; m < 4; m++)
                acc[n][m] = MFMA16(af[m], b, acc[n][m]);
        }
    }
    #pragma unroll
    for (int n = 0; n < 2; n++)
        #pragma unroll
        for (int m = 0; m < 4; m++)
            #pragma unroll
            for (int j = 0; j < 4; j++){
                int row = m0 + m*16 + hi*4 + j;
                int col = (ntbase + n)*16 + lo;
                enc_att[(size_t)row*ATT + col] = f2bf(acc[n][m][j] + be[col]);
            }
}

// ---------------------------------------------------------------------------
// K1: dg (dec_att) + Wfb-gate. grid 40 x 256.
// 4 kt per phase: 4 phases. Ring depth 4 x 32KB = 128KB LDS.
// ---------------------------------------------------------------------------
__launch_bounds__(256)
__global__ void k_hgemm(const short* __restrict__ h_in, const short* __restrict__ Wdp,
                        const short* __restrict__ Bfb,
                        const float* __restrict__ bd, const float* __restrict__ bfb,
                        float* __restrict__ dg, float* __restrict__ gateb)
{
    __shared__ short ring[4*16384];
    int tid = threadIdx.x, wv = tid>>6, lane = tid&63;
    int hi = lane>>4, lo = lane&15;
    int gw = blockIdx.x*4 + wv;
    bool isdg = (gw < 32);
    int ntl  = isdg ? gw : gw - 32;
    int bstr = isdg ? 32 : 128;
    const short* Bp = isdg ? Wdp : Bfb;
    int srow = tid>>2;
    int swc  = (tid&3) ^ ((srow>>1)&3);
    int swz  = (hi ^ ((lo>>1)&3))*8;
    auto STG = [&](int q){
        short* buf = ring + q*16384;
        #pragma unroll
        for (int j = 0; j < 4; j++){
            int kt = 4*q + j;
            stage16(h_in + (size_t)srow*512 + kt*32 + swc*8,
                    buf + j*2048 + wv*512);
            stage16(Bp + ((size_t)(kt*bstr + ntl)*64 + lane)*8,
                    buf + 8192 + wv*2048 + j*512);
        }
    };
    STG(0); STG(1); STG(2);
    f32x4 acc[4] = {};
    auto CMP = [&](int pp){
        const short* buf = ring + pp*16384;
        #pragma unroll
        for (int j = 0; j < 4; j++){
            bf16x8 b = *(const bf16x8*)(buf + 8192 + wv*2048 + j*512 + lane*8);
            const short* Ab = buf + j*2048;
            #pragma unroll
            for (int m = 0; m < 4; m++){
                bf16x8 a = *(const bf16x8*)(Ab + (m*16 + lo)*32 + swz);
                acc[m] = MFMA16(a, b, acc[m]);
            }
        }
    };
    WAITV(16); PHASE_SYNC(); STG(3); CMP(0);
    WAITV(16); PHASE_SYNC(); CMP(1);
    WAITV(8);  PHASE_SYNC(); CMP(2);
    WAITV(0);  PHASE_SYNC(); CMP(3);
    int col = ntl*16 + lo;
    if (isdg){
        #pragma unroll
        for (int m = 0; m < 4; m++)
            #pragma unroll
            for (int j = 0; j < 4; j++)
                dg[(m*16 + hi*4 + j)*512 + col] = acc[m][j] + bd[col];
    } else {
        #pragma unroll
        for (int m = 0; m < 4; m++)
            #pragma unroll
            for (int j = 0; j < 4; j++)
                gateb[(m*16 + hi*4 + j)*2048 + col] = sigmoidf_(acc[m][j] + bfb[col]);
    }
}

// ---------------------------------------------------------------------------
// K2: scores -> softmax -> alphas -> z -> gated inp. One block per b, 512 thr.
// z: 4-way l-split (49-iter chains) + LDS partial reduce (rotated writes).
// ---------------------------------------------------------------------------
__launch_bounds__(512)
__global__ void k_attnz(const float* __restrict__ dg, const short* __restrict__ encat,
                        const float* __restrict__ Wa, const float* __restrict__ ba,
                        const short* __restrict__ embs, const float* __restrict__ gateb,
                        const short* __restrict__ enc_s, const float* __restrict__ enc,
                        const int* __restrict__ sind, const int* __restrict__ lens_s,
                        short* __restrict__ inp, float* __restrict__ out_alphas,
                        int t, int fast)
{
    __shared__ float da[512];
    __shared__ float was[512];
    __shared__ float sc[200];
    __shared__ float red[16];
    __shared__ float al[200];
    __shared__ float zpart[4*2048];
    int b = blockIdx.x, tid = threadIdx.x;
    int lane = tid & 63, wv = tid >> 6;
    da[tid] = dg[b*512 + tid];
    was[tid] = Wa[tid];
    __syncthreads();
    float ba_v = ba[0];
    for (int l = wv; l < LL; l += 8){
        const short* ea = encat + ((size_t)b*LL + l)*ATT;
        float s = 0.f;
        #pragma unroll
        for (int q = 0; q < 8; q++){
            int a = lane + q*64;
            s += tanh_fast(bf2f(ea[a]) + da[a]) * was[a];
        }
        #pragma unroll
        for (int off = 32; off; off >>= 1) s += __shfl_xor(s, off);
        if (lane == 0) sc[l] = s + ba_v;
    }
    __syncthreads();
    float v = -1e30f, e = 0.f;
    if (tid < 256){
        v = (tid < LL) ? sc[tid] : -1e30f;
        float mx = v;
        #pragma unroll
        for (int off = 32; off; off >>= 1) mx = fmaxf(mx, __shfl_xor(mx, off));
        if (lane == 0) red[wv] = mx;
    }
    if (tid < 256){
        const unsigned* s32 = (const unsigned*)(embs + ((size_t)b*TM1 + t)*EMB);
        ((unsigned*)(inp + (size_t)b*2560))[tid] = s32[tid];
    }
    __syncthreads();
    float mxa = fmaxf(fmaxf(red[0], red[1]), fmaxf(red[2], red[3]));
    if (tid < 256){
        e = (tid < LL) ? __expf(v - mxa) : 0.f;
        float sm = e;
        #pragma unroll
        for (int off = 32; off; off >>= 1) sm += __shfl_xor(sm, off);
        if (lane == 0) red[8 + wv] = sm;
    }
    __syncthreads();
    float tot = red[8] + red[9] + red[10] + red[11];
    if (tid < LL){
        float alv = e / tot;
        al[tid] = alv;
        float m = (t < lens_s[b]) ? 1.f : 0.f;
        out_alphas[((size_t)b*TM1 + t)*LL + tid] = alv * m;
    }
    __syncthreads();
    // z: thread (ls, cs): ls = l-slice 0..3 (49 iters), cs = 16-col group
    {
        int ls = tid >> 7;          // 0..3
        int cs = tid & 127;         // 0..127
        int c0 = cs*16;
        float a16[16] = {};
        if (fast){
            const short* base = enc_s + ((size_t)b*LL)*ENC + c0;
            for (int l = ls; l < LL; l += 4){
                float av = al[l];
                const short* r = base + (size_t)l*ENC;
                bf16x8 v0 = *(const bf16x8*)(r);
                bf16x8 v1 = *(const bf16x8*)(r + 8);
                #pragma unroll
                for (int j = 0; j < 8; j++){
                    a16[j]     += av*bf2f(v0[j]);
                    a16[8 + j] += av*bf2f(v1[j]);
                }
            }
        } else {
            const float* base = enc + ((size_t)sind[b]*LL)*ENC + c0;
            for (int l = ls; l < LL; l += 4){
                float av = al[l];
                const float* r = base + (size_t)l*ENC;
                float4 f0 = *(const float4*)(r),     f1 = *(const float4*)(r+4);
                float4 f2 = *(const float4*)(r + 8), f3 = *(const float4*)(r+12);
                a16[0]+=av*f0.x; a16[1]+=av*f0.y; a16[2]+=av*f0.z; a16[3]+=av*f0.w;
                a16[4]+=av*f1.x; a16[5]+=av*f1.y; a16[6]+=av*f1.z; a16[7]+=av*f1.w;
                a16[8]+=av*f2.x; a16[9]+=av*f2.y; a16[10]+=av*f2.z; a16[11]+=av*f2.w;
                a16[12]+=av*f3.x; a16[13]+=av*f3.y; a16[14]+=av*f3.z; a16[15]+=av*f3.w;
            }
        }
        // rotated-order scalar writes: instruction jj writes slot (jj+cs)&15
        float* zp = zpart + ls*2048 + c0;
        #pragma unroll
        for (int jj = 0; jj < 16; jj++){
            int slot = (jj + cs) & 15;
            zp[slot] = a16[slot];
        }
    }
    __syncthreads();
    {
        int c = tid*4;
        const float* gt = gateb + (size_t)b*2048 + c;
        bf16x4 o;
        #pragma unroll
        for (int j = 0; j < 4; j++){
            float s = zpart[0*2048 + c + j] + zpart[1*2048 + c + j]
                    + zpart[2*2048 + c + j] + zpart[3*2048 + c + j];
            o[j] = f2bf(gt[j] * s);
        }
        *(bf16x4*)(inp + (size_t)b*2560 + 512 + c) = o;
    }
}

// ---------------------------------------------------------------------------
// K3: g GEMM (split-K=2) + LSTM. 32 blocks x 512 thr.
// 3 kt per phase: 16 phases. Ring DEPTH 3 x 48KB = 144KB LDS.
// ---------------------------------------------------------------------------
__launch_bounds__(512)
__global__ void k_glstm(const short* __restrict__ inp, const short* __restrict__ h_in,
                        const short* __restrict__ Bg, const float* __restrict__ bsum,
                        float* __restrict__ c, short* __restrict__ h_out)
{
    __shared__ short ring[3*24576];           // 144KB; gs unioned in after loop
    float* gs = (float*)ring;
    int tid = threadIdx.x, wv = tid>>6, lane = tid&63;
    int hi = lane>>4, lo = lane&15;
    int gate = wv & 3, khalf = wv >> 2;
    int j16 = blockIdx.x;
    int nt = gate*32 + j16;
    int sl   = tid >> 8;             // A-slice group (khalf) this thread stages
    int st   = tid & 255;
    int srow = st >> 2;
    int swc  = (st&3) ^ ((srow>>1)&3);
    int swz  = (hi ^ ((lo>>1)&3))*8;
    auto STG = [&](int q){
        short* buf = ring + (q%3)*24576;
        #pragma unroll
        for (int j = 0; j < 3; j++){
            int kt = sl*48 + 3*q + j;
            const short* src;
            if (kt < 80) src = inp  + (size_t)srow*2560 + kt*32 + swc*8;
            else         src = h_in + (size_t)srow*512  + (kt-80)*32 + swc*8;
            stage16(src, buf + (sl*3 + j)*2048 + (wv&3)*512);
            int ktw = khalf*48 + 3*q + j;
            stage16(Bg + ((size_t)(ktw*128 + nt)*64 + lane)*8,
                    buf + 12288 + wv*1536 + j*512);
        }
    };
    STG(0); STG(1);
    f32x4 acc[4] = {};
    auto CMP = [&](int pp){
        const short* buf = ring + (pp%3)*24576;
        #pragma unroll
        for (int j = 0; j < 3; j++){
            bf16x8 b = *(const bf16x8*)(buf + 12288 + wv*1536 + j*512 + lane*8);
            const short* Ab = buf + (khalf*3 + j)*2048;
            #pragma unroll
            for (int m = 0; m < 4; m++){
                bf16x8 a = *(const bf16x8*)(Ab + (m*16 + lo)*32 + swz);
                acc[m] = MFMA16(a, b, acc[m]);
            }
        }
    };
    for (int pp = 0; pp < 14; pp++){
        WAITV(6); PHASE_SYNC();
        STG(pp + 2);
        CMP(pp);
    }
    WAITV(6); PHASE_SYNC(); CMP(14);
    WAITV(0); PHASE_SYNC(); CMP(15);
    __syncthreads();                 // all ring reads done before gs overwrite
    #pragma unroll
    for (int m = 0; m < 4; m++)
        #pragma unroll
        for (int j = 0; j < 4; j++)
            gs[wv*1088 + (m*16 + hi*4 + j)*17 + lo] = acc[m][j];
    __syncthreads();
    #pragma unroll
    for (int rep = 0; rep < 2; rep++){
        int idx = rep*512 + tid;
        int row = idx >> 4, cl = idx & 15;
        int col = j16*16 + cl;
        float s0 = gs[0*1088 + row*17 + cl] + gs[4*1088 + row*17 + cl] + bsum[col];
        float s1 = gs[1*1088 + row*17 + cl] + gs[5*1088 + row*17 + cl] + bsum[512 + col];
        float s2 = gs[2*1088 + row*17 + cl] + gs[6*1088 + row*17 + cl] + bsum[1024 + col];
        float s3 = gs[3*1088 + row*17 + cl] + gs[7*1088 + row*17 + cl] + bsum[1536 + col];
        int ci = row*512 + col;
        float cn = sigmoidf_(s1)*c[ci] + sigmoidf_(s0)*tanh_fast(s2);
        c[ci] = cn;
        h_out[ci] = f2bf(sigmoidf_(s3)*tanh_fast(cn));
    }
}

// ---------------------------------------------------------------------------
// K4: batched pred GEMM. grid (313, 13): 2 mt per block (last block 1).
// 2.6x more waves than (313,5) to cover the vmcnt chain latency.
// Counted tail drain generalized to runtime phase count NP.
// ---------------------------------------------------------------------------
__launch_bounds__(256)
__global__ void k_predall(const short* __restrict__ hh, const short* __restrict__ Wfcb,
                          const float* __restrict__ bfc, const int* __restrict__ lens_s,
                          float* __restrict__ out_preds)
{
    __shared__ short ring[4*2048];
    int tid = threadIdx.x, wv = tid>>6, lane = tid&63;
    int hi = lane>>4, lo = lane&15;
    int nt = blockIdx.x*4 + wv;
    if (nt > 1249) nt = 1249;        // duplicate work; identical values stored
    int mt0 = blockIdx.y*2;
    int nmt = (mt0 + 2 <= TM1) ? 2 : 1;
    int NP = nmt*16;
    bf16x8 breg[16];
    #pragma unroll
    for (int kt = 0; kt < 16; kt++)
        breg[kt] = *(const bf16x8*)(Wfcb + ((size_t)(kt*1250 + nt)*64 + lane)*8);
    int col = nt*16 + lo;
    float bv = bfc[col];
    int lv[16];
    #pragma unroll
    for (int m = 0; m < 4; m++)
        #pragma unroll
        for (int j = 0; j < 4; j++)
            lv[m*4 + j] = lens_s[m*16 + hi*4 + j];

    int srow = tid>>2;
    int swc  = (tid&3) ^ ((srow>>1)&3);
    int swz  = (hi ^ ((lo>>1)&3))*8;
    const short* hh0 = hh + (size_t)(mt0 + 1)*(BB*DEC);
    auto STG = [&](int q){
        const short* src = hh0 + (size_t)(q>>4)*(BB*DEC) + (size_t)srow*512
                         + (q&15)*32 + swc*8;
        stage16(src, ring + (q&3)*2048 + wv*512);
    };
    STG(0); STG(1); STG(2);

    auto CMP = [&](f32x4* acc, int kt, int pp){
        const short* base = ring + (pp&3)*2048;
        #pragma unroll
        for (int m = 0; m < 4; m++){
            bf16x8 a = *(const bf16x8*)(base + (m*16 + lo)*32 + swz);
            acc[m] = MFMA16(a, breg[kt], acc[m]);
        }
    };
    auto STORE = [&](f32x4* acc, int mta){
        #pragma unroll
        for (int m = 0; m < 4; m++)
            #pragma unroll
            for (int j = 0; j < 4; j++){
                int row = m*16 + hi*4 + j;
                float mk = (mta < lv[m*4 + j]) ? 1.f : 0.f;
                out_preds[((size_t)row*TM1 + mta)*VV + col] = mk*(acc[m][j] + bv);
            }
    };

    for (int mt = 0; mt < nmt; mt++){
        f32x4 acc[4] = {};
        #pragma unroll
        for (int kt = 0; kt < 16; kt++){
            int pp = mt*16 + kt;
            if (pp < NP - 2)      { WAITV(2); }
            else if (pp == NP - 2){ WAITV(1); }
            else                  { WAITV(0); }
            PHASE_SYNC();
            if (pp + 3 < NP) STG(pp + 3);
            CMP(acc, kt, pp);
        }
        STORE(acc, mt0 + mt);
    }
}

// ---------------------------------------------------------------------------
extern "C" void kernel_launch(void* const* d_in, const int* in_sizes, int n_in,
                              void* d_out, int out_size, void* d_ws, size_t ws_size,
                              hipStream_t stream)
{
    const float* enc  = (const float*)d_in[0];
    const int*   cap  = (const int*)  d_in[1];
    const int*   clen = (const int*)  d_in[2];
    const float* embW = (const float*)d_in[3];
    const float* We   = (const float*)d_in[4];
    const float* be   = (const float*)d_in[5];
    const float* Wd   = (const float*)d_in[6];
    const float* bd   = (const float*)d_in[7];
    const float* Wa   = (const float*)d_in[8];
    const float* ba   = (const float*)d_in[9];
    const float* Wih  = (const float*)d_in[10];
    const float* bih  = (const float*)d_in[11];
    const float* Whh  = (const float*)d_in[12];
    const float* bhh  = (const float*)d_in[13];
    const float* Wfb  = (const float*)d_in[14];
    const float* bfb  = (const float*)d_in[15];
    const float* Wh0  = (const float*)d_in[16];
    const float* bh0  = (const float*)d_in[17];
    const float* Wc0  = (const float*)d_in[18];
    const float* bc0  = (const float*)d_in[19];
    const float* Wfc  = (const float*)d_in[20];
    const float* bfc  = (const float*)d_in[21];

    char* w = (char*)d_ws;
    size_t cur = 0;
    auto alloc = [&](size_t bytes)->char*{
        char* p = w + cur; cur = (cur + bytes + 255) & ~(size_t)255; return p;
    };
    int*   sind   = (int*)  alloc(256);
    int*   lens_s = (int*)  alloc(256);
    float* bsum   = (float*)alloc(4*DEC*4);
    float* mean   = (float*)alloc(BB*ENC*4);
    float* hpart  = (float*)alloc((size_t)8*64*1024*4);
    float* c      = (float*)alloc(BB*DEC*4);
    short* hh     = (short*)alloc((size_t)(TM1+1)*BB*DEC*2);
    float* dg     = (float*)alloc(BB*512*4);
    float* gateb  = (float*)alloc(BB*2048*4);
    short* inp    = (short*)alloc(BB*2560*2);
    short* embs   = (short*)alloc((size_t)BB*TM1*EMB*2);
    short* Wdp    = (short*)alloc((size_t)512*512*2);
    short* Web    = (short*)alloc((size_t)ENC*ATT*2);
    short* Bfb    = (short*)alloc((size_t)512*2048*2);
    short* Bg     = (short*)alloc((size_t)3072*2048*2);
    short* Wfcb   = (short*)alloc((size_t)512*VV*2);
    short* encat  = (short*)alloc((size_t)BB*LL*ATT*2);
    short* enc_s  = (short*)alloc((size_t)BB*LL*ENC*2);
    bool fast = (ws_size >= cur);
    int fastI = fast ? 1 : 0;

    float* out        = (float*)d_out;
    float* out_preds  = out;
    float* out_alphas = out + 32000000ull;
    float* out_cap    = out + 32313600ull;
    float* out_lens   = out + 32315264ull;

    // ---- prologue ----
    k_sort<<<1, 64, 0, stream>>>(clen, cap, bih, bhh, sind, lens_s, bsum,
                                 out_cap, out_lens);
    PrepArgs P;
    P.enc = enc; P.sind = sind; P.enc_s = enc_s;
    P.Wfc = Wfc; P.Wfcb = Wfcb;
    P.Wih = Wih; P.Whh = Whh; P.Bg = Bg;
    P.We = We; P.Web = Web;
    P.Wfb = Wfb; P.Bfb = Bfb;
    P.Wd = Wd; P.Wdp = Wdp;
    P.mean = mean;
    P.embW = embW; P.cap = cap; P.embs = embs;
    P.fast = fastI;
    P.blkoff = 0;
    k_prep<<<SEG0, 256, 0, stream>>>(P);          // enc conversion half
    PrepArgs P2 = P;
    P2.blkoff = SEG0;
    k_prep<<<SEG8 - SEG0, 256, 0, stream>>>(P2);  // weight-pack half

    k_h0part<<<dim3(16, 8), 256, 0, stream>>>(mean, Wh0, Wc0, hpart);
    k_h0fin<<<256, 256, 0, stream>>>(hpart, bh0, bc0, hh, c);

    if (fast)
        k_encatt_mfma<true ><<<dim3(196, 4), 256, 0, stream>>>(enc_s, sind, Web, be, encat);
    else
        k_encatt_mfma<false><<<dim3(196, 4), 256, 0, stream>>>(enc,   sind, Web, be, encat);

    // ---- decode loop: 3 dispatches per step ----
    for (int t = 0; t < TM1; t++){
        const short* h_in  = hh + (size_t)t*(BB*DEC);
        short*       h_out = hh + (size_t)(t+1)*(BB*DEC);
        k_hgemm<<<40, 256, 0, stream>>>(h_in, Wdp, Bfb, bd, bfb, dg, gateb);
        k_attnz<<<64, 512, 0, stream>>>(dg, encat, Wa, ba, embs, gateb, enc_s, enc,
                                        sind, lens_s, inp, out_alphas, t, fastI);
        k_glstm<<<32, 512, 0, stream>>>(inp, h_in, Bg, bsum, c, h_out);
    }
    // ---- batched pred GEMM over all steps ----
    k_predall<<<dim3(313, 13), 256, 0, stream>>>(hh, Wfcb, bfc, lens_s, out_preds);
}

// Round 10
// 1856.153 us; speedup vs baseline: 1.5576x; 1.0105x over previous
//
#include <hip/hip_runtime.h>
#include <hip/hip_bf16.h>

#define BB 64
#define LL 196
#define ENC 2048
#define DEC 512
#define EMB 512
#define ATT 512
#define VV 20000
#define TT 26
#define TM1 25

typedef __attribute__((ext_vector_type(8))) short bf16x8;
typedef __attribute__((ext_vector_type(4))) short bf16x4;
typedef __attribute__((ext_vector_type(4))) float f32x4;

#define MFMA16(a,b,c) __builtin_amdgcn_mfma_f32_16x16x32_bf16(a,b,c,0,0,0)

typedef const __attribute__((address_space(1))) void g_void;
typedef __attribute__((address_space(3))) void l_void;

// async global->LDS, 16B per lane; dest is wave-uniform base + lane*16
__device__ __forceinline__ void stage16(const void* g, void* l){
    __builtin_amdgcn_global_load_lds((g_void*)g, (l_void*)l, 16, 0, 0);
}

#define WAITV(N) asm volatile("s_waitcnt vmcnt(" #N ")" ::: "memory")
#define PHASE_SYNC() do { __builtin_amdgcn_s_barrier(); __builtin_amdgcn_sched_barrier(0); } while(0)

__device__ __forceinline__ float tanh_fast(float x){
    float ax = fabsf(x);
    float e  = __expf(-2.f*ax);
    float r  = (1.f - e)/(1.f + e);
    return x >= 0.f ? r : -r;
}
__device__ __forceinline__ float sigmoidf_(float x){
    return 1.f/(1.f + __expf(-x));
}
__device__ __forceinline__ short f2bf(float v){
    __hip_bfloat16 b = __float2bfloat16(v);
    return __builtin_bit_cast(short, b);
}
__device__ __forceinline__ float bf2f(short s){
    __hip_bfloat16 b = __builtin_bit_cast(__hip_bfloat16, s);
    return __bfloat162float(b);
}

// ---------------------------------------------------------------------------
// sort + cap/lens outputs + bias_sum
// ---------------------------------------------------------------------------
__global__ void k_sort(const int* __restrict__ clen, const int* __restrict__ cap,
                       const float* __restrict__ bih, const float* __restrict__ bhh,
                       int* __restrict__ sind, int* __restrict__ lens_s,
                       float* __restrict__ bsum,
                       float* __restrict__ out_cap, float* __restrict__ out_lens)
{
    int i = threadIdx.x;
    int li = clen[i];
    int r = 0;
    for (int j = 0; j < BB; j++){
        int lj = clen[j];
        r += (lj > li) || (lj == li && j < i);
    }
    sind[r] = i;
    lens_s[r] = li - 1;
    out_lens[r] = (float)(li - 1);
    for (int t = 0; t < TT; t++)
        out_cap[r*TT + t] = (float)cap[i*TT + t];
    for (int j = i; j < 4*DEC; j += BB)
        bsum[j] = bih[j] + bhh[j];
}

// ---------------------------------------------------------------------------
// k_prep: all packs / conversions / mean / embedding (segmented, 2 launches)
// ---------------------------------------------------------------------------
struct PrepArgs {
    const float* enc; const int* sind; short* enc_s;
    const float* Wfc; short* Wfcb;
    const float* Wih; const float* Whh; short* Bg;
    const float* We;  short* Web;
    const float* Wfb; short* Bfb;
    const float* Wd;  short* Wdp;
    float* mean;
    const float* embW; const int* cap; short* embs;
    int fast; int blkoff;
};

#define SEG0 12544               // cvt_enc
#define SEG1 (SEG0 + 5000)       // Wfc pack
#define SEG2 (SEG1 + 2560)       // Wih pack
#define SEG3 (SEG2 + 512)        // We pack
#define SEG4 (SEG3 + 512)        // Wfb pack
#define SEG5 (SEG4 + 512)        // Whh pack
#define SEG6 (SEG5 + 512)        // mean
#define SEG7 (SEG6 + 1600)       // emb
#define SEG8 (SEG7 + 128)        // Wd pack

__device__ __forceinline__ void pack_frag(int idx, const float* src, int ld,
                                          int K, int N, short* dst,
                                          int ktOff, int ntOff, int ntTot, bool NK)
{
    int ntCnt = N >> 4, ktCnt = K >> 5;
    int lane = idx & 63, rest = idx >> 6;
    if (rest >= ktCnt*ntCnt) return;
    int nt = rest % ntCnt, kt = rest / ntCnt;
    int k = kt*32 + (lane>>4)*8, n = nt*16 + (lane&15);
    bf16x8 v;
    #pragma unroll
    for (int j = 0; j < 8; j++){
        float f = NK ? src[(size_t)n*ld + k + j] : src[(size_t)(k+j)*ld + n];
        v[j] = f2bf(f);
    }
    *(bf16x8*)(dst + ((size_t)((kt+ktOff)*ntTot + (nt+ntOff))*64 + lane)*8) = v;
}

__launch_bounds__(256)
__global__ void k_prep(PrepArgs P)
{
    int blk = blockIdx.x + P.blkoff, tid = threadIdx.x;
    if (blk < SEG0){
        if (!P.fast) return;
        size_t idx = ((size_t)blk*256 + tid)*8;
        int r = (int)(idx / (LL*ENC));
        size_t rem = idx - (size_t)r*(LL*ENC);
        const float* s = P.enc + (size_t)P.sind[r]*(LL*ENC) + rem;
        bf16x8 v;
        float4 f0 = *(const float4*)s, f1 = *(const float4*)(s+4);
        v[0]=f2bf(f0.x); v[1]=f2bf(f0.y); v[2]=f2bf(f0.z); v[3]=f2bf(f0.w);
        v[4]=f2bf(f1.x); v[5]=f2bf(f1.y); v[6]=f2bf(f1.z); v[7]=f2bf(f1.w);
        *(bf16x8*)(P.enc_s + idx) = v;
    } else if (blk < SEG1){
        pack_frag((blk-SEG0)*256 + tid, P.Wfc, VV, 512, VV, P.Wfcb, 0, 0, 1250, false);
    } else if (blk < SEG2){
        pack_frag((blk-SEG1)*256 + tid, P.Wih, 2560, 2560, 2048, P.Bg, 0, 0, 128, true);
    } else if (blk < SEG3){
        pack_frag((blk-SEG2)*256 + tid, P.We, ATT, ENC, ATT, P.Web, 0, 0, 32, false);
    } else if (blk < SEG4){
        pack_frag((blk-SEG3)*256 + tid, P.Wfb, ENC, 512, 2048, P.Bfb, 0, 0, 128, false);
    } else if (blk < SEG5){
        pack_frag((blk-SEG4)*256 + tid, P.Whh, 512, 512, 2048, P.Bg, 80, 0, 128, true);
    } else if (blk < SEG6){
        int rel = blk - SEG5;           // 0..511
        int b = rel >> 3;
        int e = (rel & 7)*256 + tid;
        int sb = P.sind[b];
        const float* p = P.enc + ((size_t)sb*LL)*ENC + e;
        float s = 0.f;
        for (int l = 0; l < LL; l++) s += p[(size_t)l*ENC];
        P.mean[b*ENC + e] = s * (1.f/(float)LL);
    } else if (blk < SEG7){
        int rel = blk - SEG6;           // (b, t)
        int b = rel / 25, t = rel % 25;
        int token = P.cap[P.sind[b]*TT + t];
        const float* src = P.embW + (size_t)token*EMB + tid*2;
        unsigned u = (unsigned)(unsigned short)f2bf(src[0]) |
                     ((unsigned)(unsigned short)f2bf(src[1]) << 16);
        ((unsigned*)(P.embs + ((size_t)b*TM1 + t)*EMB))[tid] = u;
    } else if (blk < SEG8){
        pack_frag((blk-SEG7)*256 + tid, P.Wd, ATT, 512, 512, P.Wdp, 0, 0, 32, false);
    }
}

// ---------------------------------------------------------------------------
// h0/c0 split-K fp32
// ---------------------------------------------------------------------------
#define KT 32
__launch_bounds__(256)
__global__ void k_h0part(const float* __restrict__ A1, const float* __restrict__ B1,
                         const float* __restrict__ B2, float* __restrict__ hpart)
{
    __shared__ float As[KT][64];
    __shared__ float Bs[KT][64];
    const int tid = threadIdx.x;
    const int n0  = blockIdx.x*64;
    const int kq  = blockIdx.y;
    float acc[4][4] = {};
    const int lrow = tid >> 3, lcol = tid & 7;
    const int bn = (tid & 15)*4, bk = tid >> 4;
    const int bi0 = (tid >> 4)*4, nj0 = (tid & 15)*4;
    for (int k0 = kq*256; k0 < kq*256 + 256; k0 += KT){
        #pragma unroll
        for (int p = 0; p < 2; p++){
            int m = lrow + p*32;
            float4 v = *(const float4*)(A1 + (size_t)m*2048 + k0 + lcol*4);
            As[lcol*4+0][m] = v.x; As[lcol*4+1][m] = v.y;
            As[lcol*4+2][m] = v.z; As[lcol*4+3][m] = v.w;
        }
        {
            bool hi = (n0 >= 512);
            const float* B = hi ? B2 : B1;
            int ncol = n0 - (hi ? 512 : 0) + bn;
            #pragma unroll
            for (int p = 0; p < 2; p++){
                int k = bk + p*16;
                *(float4*)&Bs[k][bn] = *(const float4*)(B + (size_t)(k0+k)*512 + ncol);
            }
        }
        __syncthreads();
        #pragma unroll
        for (int k = 0; k < KT; k++){
            const float4 av = *(const float4*)&As[k][bi0];
            const float4 bv = *(const float4*)&Bs[k][nj0];
            acc[0][0] += av.x*bv.x; acc[0][1] += av.x*bv.y; acc[0][2] += av.x*bv.z; acc[0][3] += av.x*bv.w;
            acc[1][0] += av.y*bv.x; acc[1][1] += av.y*bv.y; acc[1][2] += av.y*bv.z; acc[1][3] += av.y*bv.w;
            acc[2][0] += av.z*bv.x; acc[2][1] += av.z*bv.y; acc[2][2] += av.z*bv.z; acc[2][3] += av.z*bv.w;
            acc[3][0] += av.w*bv.x; acc[3][1] += av.w*bv.y; acc[3][2] += av.w*bv.z; acc[3][3] += av.w*bv.w;
        }
        __syncthreads();
    }
    #pragma unroll
    for (int i = 0; i < 4; i++)
        #pragma unroll
        for (int j = 0; j < 4; j++){
            int b = bi0 + i, n = n0 + nj0 + j;
            hpart[((size_t)kq*64 + b)*1024 + n] = acc[i][j];
        }
}

__global__ void k_h0fin(const float* __restrict__ hpart, const float* __restrict__ bh0,
                        const float* __restrict__ bc0, short* __restrict__ h0,
                        float* __restrict__ c)
{
    int idx = blockIdx.x*256 + threadIdx.x;
    int b = idx >> 10, n = idx & 1023;
    float v = (n < 512) ? bh0[n] : bc0[n-512];
    for (int kq = 0; kq < 8; kq++) v += hpart[((size_t)kq*64 + b)*1024 + n];
    float r = tanh_fast(v);
    if (n < 512) h0[b*512 + n] = f2bf(r);
    else         c[b*512 + (n-512)] = r;
}

// ---------------------------------------------------------------------------
// enc_att MFMA: grid (196,4), 2 nt per wave
// ---------------------------------------------------------------------------
template<bool BF16SRC>
__launch_bounds__(256)
__global__ void k_encatt_mfma(const void* __restrict__ encp, const int* __restrict__ sind,
                              const short* __restrict__ Web, const float* __restrict__ be,
                              short* __restrict__ enc_att)
{
    __shared__ short As[64*32];
    int tid = threadIdx.x, wv = tid>>6, lane = tid&63;
    int hi = lane>>4, lo = lane&15;
    int m0 = blockIdx.x*64;
    int ntbase = blockIdx.y*8 + wv*2;
    int srow = tid>>2, schunk = tid&3;
    const short* gsrcB = nullptr; const float* gsrcF = nullptr;
    if (BF16SRC){
        gsrcB = (const short*)encp + (size_t)(m0+srow)*ENC + schunk*8;
    } else {
        int grow = m0 + srow;
        int b = grow/LL, l = grow - b*LL;
        gsrcF = (const float*)encp + ((size_t)sind[b]*LL + l)*ENC + schunk*8;
    }
    int sws = srow*32 + (schunk ^ ((srow>>1)&3))*8;
    f32x4 acc[2][4] = {};
    for (int kt = 0; kt < 64; kt++){
        bf16x8 v;
        if (BF16SRC){
            v = *(const bf16x8*)(gsrcB + kt*32);
        } else {
            float4 f0 = *(const float4*)(gsrcF + kt*32);
            float4 f1 = *(const float4*)(gsrcF + kt*32 + 4);
            v[0]=f2bf(f0.x); v[1]=f2bf(f0.y); v[2]=f2bf(f0.z); v[3]=f2bf(f0.w);
            v[4]=f2bf(f1.x); v[5]=f2bf(f1.y); v[6]=f2bf(f1.z); v[7]=f2bf(f1.w);
        }
        __syncthreads();
        *(bf16x8*)(As + sws) = v;
        __syncthreads();
        bf16x8 af[4];
        #pragma unroll
        for (int m = 0; m < 4; m++){
            int r = m*16 + lo;
            af[m] = *(const bf16x8*)(As + r*32 + (hi ^ ((r>>1)&3))*8);
        }
        #pragma unroll
        for (int n = 0; n < 2; n++){
            bf16x8 b = *(const bf16x8*)(Web + ((size_t)(kt*32 + ntbase + n)*64 + lane)*8);
            #pragma unroll
            for (int m = 0; m < 4; m++)
                acc[n][m] = MFMA16(af[m], b, acc[n][m]);
        }
    }
    #pragma unroll
    for (int n = 0; n < 2; n++)
        #pragma unroll
        for (int m = 0; m < 4; m++)
            #pragma unroll
            for (int j = 0; j < 4; j++){
                int row = m0 + m*16 + hi*4 + j;
                int col = (ntbase + n)*16 + lo;
                enc_att[(size_t)row*ATT + col] = f2bf(acc[n][m][j] + be[col]);
            }
}

// ---------------------------------------------------------------------------
// K1: dg (dec_att) + Wfb-gate. grid 40 x 256.
// 4 kt per phase: 4 phases. Ring depth 4 x 32KB = 128KB LDS.
// ---------------------------------------------------------------------------
__launch_bounds__(256)
__global__ void k_hgemm(const short* __restrict__ h_in, const short* __restrict__ Wdp,
                        const short* __restrict__ Bfb,
                        const float* __restrict__ bd, const float* __restrict__ bfb,
                        float* __restrict__ dg, float* __restrict__ gateb)
{
    __shared__ short ring[4*16384];
    int tid = threadIdx.x, wv = tid>>6, lane = tid&63;
    int hi = lane>>4, lo = lane&15;
    int gw = blockIdx.x*4 + wv;
    bool isdg = (gw < 32);
    int ntl  = isdg ? gw : gw - 32;
    int bstr = isdg ? 32 : 128;
    const short* Bp = isdg ? Wdp : Bfb;
    int srow = tid>>2;
    int swc  = (tid&3) ^ ((srow>>1)&3);
    int swz  = (hi ^ ((lo>>1)&3))*8;
    auto STG = [&](int q){
        short* buf = ring + q*16384;
        #pragma unroll
        for (int j = 0; j < 4; j++){
            int kt = 4*q + j;
            stage16(h_in + (size_t)srow*512 + kt*32 + swc*8,
                    buf + j*2048 + wv*512);
            stage16(Bp + ((size_t)(kt*bstr + ntl)*64 + lane)*8,
                    buf + 8192 + wv*2048 + j*512);
        }
    };
    STG(0); STG(1); STG(2);
    f32x4 acc[4] = {};
    auto CMP = [&](int pp){
        const short* buf = ring + pp*16384;
        #pragma unroll
        for (int j = 0; j < 4; j++){
            bf16x8 b = *(const bf16x8*)(buf + 8192 + wv*2048 + j*512 + lane*8);
            const short* Ab = buf + j*2048;
            #pragma unroll
            for (int m = 0; m < 4; m++){
                bf16x8 a = *(const bf16x8*)(Ab + (m*16 + lo)*32 + swz);
                acc[m] = MFMA16(a, b, acc[m]);
            }
        }
    };
    WAITV(16); PHASE_SYNC(); STG(3); CMP(0);
    WAITV(16); PHASE_SYNC(); CMP(1);
    WAITV(8);  PHASE_SYNC(); CMP(2);
    WAITV(0);  PHASE_SYNC(); CMP(3);
    int col = ntl*16 + lo;
    if (isdg){
        #pragma unroll
        for (int m = 0; m < 4; m++)
            #pragma unroll
            for (int j = 0; j < 4; j++)
                dg[(m*16 + hi*4 + j)*512 + col] = acc[m][j] + bd[col];
    } else {
        #pragma unroll
        for (int m = 0; m < 4; m++)
            #pragma unroll
            for (int j = 0; j < 4; j++)
                gateb[(m*16 + hi*4 + j)*2048 + col] = sigmoidf_(acc[m][j] + bfb[col]);
    }
}

// ---------------------------------------------------------------------------
// K2: scores -> softmax -> alphas -> z -> gated inp. One block per b, 512 thr.
// z: 4-way l-split (49-iter chains) + LDS partial reduce (rotated writes).
// ---------------------------------------------------------------------------
__launch_bounds__(512)
__global__ void k_attnz(const float* __restrict__ dg, const short* __restrict__ encat,
                        const float* __restrict__ Wa, const float* __restrict__ ba,
                        const short* __restrict__ embs, const float* __restrict__ gateb,
                        const short* __restrict__ enc_s, const float* __restrict__ enc,
                        const int* __restrict__ sind, const int* __restrict__ lens_s,
                        short* __restrict__ inp, float* __restrict__ out_alphas,
                        int t, int fast)
{
    __shared__ float da[512];
    __shared__ float was[512];
    __shared__ float sc[200];
    __shared__ float red[16];
    __shared__ float al[200];
    __shared__ float zpart[4*2048];
    int b = blockIdx.x, tid = threadIdx.x;
    int lane = tid & 63, wv = tid >> 6;
    da[tid] = dg[b*512 + tid];
    was[tid] = Wa[tid];
    __syncthreads();
    float ba_v = ba[0];
    for (int l = wv; l < LL; l += 8){
        const short* ea = encat + ((size_t)b*LL + l)*ATT;
        float s = 0.f;
        #pragma unroll
        for (int q = 0; q < 8; q++){
            int a = lane + q*64;
            s += tanh_fast(bf2f(ea[a]) + da[a]) * was[a];
        }
        #pragma unroll
        for (int off = 32; off; off >>= 1) s += __shfl_xor(s, off);
        if (lane == 0) sc[l] = s + ba_v;
    }
    __syncthreads();
    float v = -1e30f, e = 0.f;
    if (tid < 256){
        v = (tid < LL) ? sc[tid] : -1e30f;
        float mx = v;
        #pragma unroll
        for (int off = 32; off; off >>= 1) mx = fmaxf(mx, __shfl_xor(mx, off));
        if (lane == 0) red[wv] = mx;
    }
    if (tid < 256){
        const unsigned* s32 = (const unsigned*)(embs + ((size_t)b*TM1 + t)*EMB);
        ((unsigned*)(inp + (size_t)b*2560))[tid] = s32[tid];
    }
    __syncthreads();
    float mxa = fmaxf(fmaxf(red[0], red[1]), fmaxf(red[2], red[3]));
    if (tid < 256){
        e = (tid < LL) ? __expf(v - mxa) : 0.f;
        float sm = e;
        #pragma unroll
        for (int off = 32; off; off >>= 1) sm += __shfl_xor(sm, off);
        if (lane == 0) red[8 + wv] = sm;
    }
    __syncthreads();
    float tot = red[8] + red[9] + red[10] + red[11];
    if (tid < LL){
        float alv = e / tot;
        al[tid] = alv;
        float m = (t < lens_s[b]) ? 1.f : 0.f;
        out_alphas[((size_t)b*TM1 + t)*LL + tid] = alv * m;
    }
    __syncthreads();
    // z: thread (ls, cs): ls = l-slice 0..3 (49 iters), cs = 16-col group
    {
        int ls = tid >> 7;          // 0..3
        int cs = tid & 127;         // 0..127
        int c0 = cs*16;
        float a16[16] = {};
        if (fast){
            const short* base = enc_s + ((size_t)b*LL)*ENC + c0;
            for (int l = ls; l < LL; l += 4){
                float av = al[l];
                const short* r = base + (size_t)l*ENC;
                bf16x8 v0 = *(const bf16x8*)(r);
                bf16x8 v1 = *(const bf16x8*)(r + 8);
                #pragma unroll
                for (int j = 0; j < 8; j++){
                    a16[j]     += av*bf2f(v0[j]);
                    a16[8 + j] += av*bf2f(v1[j]);
                }
            }
        } else {
            const float* base = enc + ((size_t)sind[b]*LL)*ENC + c0;
            for (int l = ls; l < LL; l += 4){
                float av = al[l];
                const float* r = base + (size_t)l*ENC;
                float4 f0 = *(const float4*)(r),     f1 = *(const float4*)(r+4);
                float4 f2 = *(const float4*)(r + 8), f3 = *(const float4*)(r+12);
                a16[0]+=av*f0.x; a16[1]+=av*f0.y; a16[2]+=av*f0.z; a16[3]+=av*f0.w;
                a16[4]+=av*f1.x; a16[5]+=av*f1.y; a16[6]+=av*f1.z; a16[7]+=av*f1.w;
                a16[8]+=av*f2.x; a16[9]+=av*f2.y; a16[10]+=av*f2.z; a16[11]+=av*f2.w;
                a16[12]+=av*f3.x; a16[13]+=av*f3.y; a16[14]+=av*f3.z; a16[15]+=av*f3.w;
            }
        }
        // rotated-order scalar writes: instruction jj writes slot (jj+cs)&15
        float* zp = zpart + ls*2048 + c0;
        #pragma unroll
        for (int jj = 0; jj < 16; jj++){
            int slot = (jj + cs) & 15;
            zp[slot] = a16[slot];
        }
    }
    __syncthreads();
    {
        int c = tid*4;
        const float* gt = gateb + (size_t)b*2048 + c;
        bf16x4 o;
        #pragma unroll
        for (int j = 0; j < 4; j++){
            float s = zpart[0*2048 + c + j] + zpart[1*2048 + c + j]
                    + zpart[2*2048 + c + j] + zpart[3*2048 + c + j];
            o[j] = f2bf(gt[j] * s);
        }
        *(bf16x4*)(inp + (size_t)b*2560 + 512 + c) = o;
    }
}

// ---------------------------------------------------------------------------
// K3: g GEMM (split-K=2) + LSTM. 32 blocks x 512 thr.
// 3 kt per phase: 16 phases. Ring DEPTH 3 x 48KB = 144KB LDS.
// ---------------------------------------------------------------------------
__launch_bounds__(512)
__global__ void k_glstm(const short* __restrict__ inp, const short* __restrict__ h_in,
                        const short* __restrict__ Bg, const float* __restrict__ bsum,
                        float* __restrict__ c, short* __restrict__ h_out)
{
    __shared__ short ring[3*24576];           // 144KB; gs unioned in after loop
    float* gs = (float*)ring;
    int tid = threadIdx.x, wv = tid>>6, lane = tid&63;
    int hi = lane>>4, lo = lane&15;
    int gate = wv & 3, khalf = wv >> 2;
    int j16 = blockIdx.x;
    int nt = gate*32 + j16;
    int sl   = tid >> 8;             // A-slice group (khalf) this thread stages
    int st   = tid & 255;
    int srow = st >> 2;
    int swc  = (st&3) ^ ((srow>>1)&3);
    int swz  = (hi ^ ((lo>>1)&3))*8;
    auto STG = [&](int q){
        short* buf = ring + (q%3)*24576;
        #pragma unroll
        for (int j = 0; j < 3; j++){
            int kt = sl*48 + 3*q + j;
            const short* src;
            if (kt < 80) src = inp  + (size_t)srow*2560 + kt*32 + swc*8;
            else         src = h_in + (size_t)srow*512  + (kt-80)*32 + swc*8;
            stage16(src, buf + (sl*3 + j)*2048 + (wv&3)*512);
            int ktw = khalf*48 + 3*q + j;
            stage16(Bg + ((size_t)(ktw*128 + nt)*64 + lane)*8,
                    buf + 12288 + wv*1536 + j*512);
        }
    };
    STG(0); STG(1);
    f32x4 acc[4] = {};
    auto CMP = [&](int pp){
        const short* buf = ring + (pp%3)*24576;
        #pragma unroll
        for (int j = 0; j < 3; j++){
            bf16x8 b = *(const bf16x8*)(buf + 12288 + wv*1536 + j*512 + lane*8);
            const short* Ab = buf + (khalf*3 + j)*2048;
            #pragma unroll
            for (int m = 0; m < 4; m++){
                bf16x8 a = *(const bf16x8*)(Ab + (m*16 + lo)*32 + swz);
                acc[m] = MFMA16(a, b, acc[m]);
            }
        }
    };
    for (int pp = 0; pp < 14; pp++){
        WAITV(6); PHASE_SYNC();
        STG(pp + 2);
        CMP(pp);
    }
    WAITV(6); PHASE_SYNC(); CMP(14);
    WAITV(0); PHASE_SYNC(); CMP(15);
    __syncthreads();                 // all ring reads done before gs overwrite
    #pragma unroll
    for (int m = 0; m < 4; m++)
        #pragma unroll
        for (int j = 0; j < 4; j++)
            gs[wv*1088 + (m*16 + hi*4 + j)*17 + lo] = acc[m][j];
    __syncthreads();
    #pragma unroll
    for (int rep = 0; rep < 2; rep++){
        int idx = rep*512 + tid;
        int row = idx >> 4, cl = idx & 15;
        int col = j16*16 + cl;
        float s0 = gs[0*1088 + row*17 + cl] + gs[4*1088 + row*17 + cl] + bsum[col];
        float s1 = gs[1*1088 + row*17 + cl] + gs[5*1088 + row*17 + cl] + bsum[512 + col];
        float s2 = gs[2*1088 + row*17 + cl] + gs[6*1088 + row*17 + cl] + bsum[1024 + col];
        float s3 = gs[3*1088 + row*17 + cl] + gs[7*1088 + row*17 + cl] + bsum[1536 + col];
        int ci = row*512 + col;
        float cn = sigmoidf_(s1)*c[ci] + sigmoidf_(s0)*tanh_fast(s2);
        c[ci] = cn;
        h_out[ci] = f2bf(sigmoidf_(s3)*tanh_fast(cn));
    }
}

// ---------------------------------------------------------------------------
// K4: batched pred GEMM over all 25 steps. grid (313,5) — measured optimum
// of the mt-split knob (5: 72us/58MB fetch; 13: 95us/138MB fetch; 25: 371us).
// Tail-race fixed (counted peel 2/1/0).
// ---------------------------------------------------------------------------
__launch_bounds__(256)
__global__ void k_predall(const short* __restrict__ hh, const short* __restrict__ Wfcb,
                          const float* __restrict__ bfc, const int* __restrict__ lens_s,
                          float* __restrict__ out_preds)
{
    __shared__ short ring[4*2048];
    int tid = threadIdx.x, wv = tid>>6, lane = tid&63;
    int hi = lane>>4, lo = lane&15;
    int nt = blockIdx.x*4 + wv;
    if (nt > 1249) nt = 1249;        // duplicate work; identical values stored
    int mt0 = blockIdx.y*5;
    bf16x8 breg[16];
    #pragma unroll
    for (int kt = 0; kt < 16; kt++)
        breg[kt] = *(const bf16x8*)(Wfcb + ((size_t)(kt*1250 + nt)*64 + lane)*8);
    int col = nt*16 + lo;
    float bv = bfc[col];
    int lv[16];
    #pragma unroll
    for (int m = 0; m < 4; m++)
        #pragma unroll
        for (int j = 0; j < 4; j++)
            lv[m*4 + j] = lens_s[m*16 + hi*4 + j];

    int srow = tid>>2;
    int swc  = (tid&3) ^ ((srow>>1)&3);
    int swz  = (hi ^ ((lo>>1)&3))*8;
    const short* hh0 = hh + (size_t)(mt0 + 1)*(BB*DEC);
    auto STG = [&](int q){
        const short* src = hh0 + (size_t)(q>>4)*(BB*DEC) + (size_t)srow*512
                         + (q&15)*32 + swc*8;
        stage16(src, ring + (q&3)*2048 + wv*512);
    };
    STG(0); STG(1); STG(2);

    auto CMP = [&](f32x4* acc, int kt, int pp){
        const short* base = ring + (pp&3)*2048;
        #pragma unroll
        for (int m = 0; m < 4; m++){
            bf16x8 a = *(const bf16x8*)(base + (m*16 + lo)*32 + swz);
            acc[m] = MFMA16(a, breg[kt], acc[m]);
        }
    };
    auto STORE = [&](f32x4* acc, int mta){
        #pragma unroll
        for (int m = 0; m < 4; m++)
            #pragma unroll
            for (int j = 0; j < 4; j++){
                int row = m*16 + hi*4 + j;
                float mk = (mta < lv[m*4 + j]) ? 1.f : 0.f;
                out_preds[((size_t)row*TM1 + mta)*VV + col] = mk*(acc[m][j] + bv);
            }
    };

    for (int mt = 0; mt < 4; mt++){
        f32x4 acc[4] = {};
        #pragma unroll
        for (int kt = 0; kt < 16; kt++){
            int pp = mt*16 + kt;
            WAITV(2); PHASE_SYNC();
            STG(pp + 3);
            CMP(acc, kt, pp);
        }
        STORE(acc, mt0 + mt);
    }
    {   // mt = 4 with counted tail drain
        f32x4 acc[4] = {};
        #pragma unroll
        for (int kt = 0; kt < 13; kt++){
            int pp = 64 + kt;
            WAITV(2); PHASE_SYNC();
            if (pp < 77) STG(pp + 3);
            CMP(acc, kt, pp);
        }
        WAITV(2); PHASE_SYNC(); CMP(acc, 13, 77);
        WAITV(1); PHASE_SYNC(); CMP(acc, 14, 78);
        WAITV(0); PHASE_SYNC(); CMP(acc, 15, 79);
        STORE(acc, mt0 + 4);
    }
}

// ---------------------------------------------------------------------------
extern "C" void kernel_launch(void* const* d_in, const int* in_sizes, int n_in,
                              void* d_out, int out_size, void* d_ws, size_t ws_size,
                              hipStream_t stream)
{
    const float* enc  = (const float*)d_in[0];
    const int*   cap  = (const int*)  d_in[1];
    const int*   clen = (const int*)  d_in[2];
    const float* embW = (const float*)d_in[3];
    const float* We   = (const float*)d_in[4];
    const float* be   = (const float*)d_in[5];
    const float* Wd   = (const float*)d_in[6];
    const float* bd   = (const float*)d_in[7];
    const float* Wa   = (const float*)d_in[8];
    const float* ba   = (const float*)d_in[9];
    const float* Wih  = (const float*)d_in[10];
    const float* bih  = (const float*)d_in[11];
    const float* Whh  = (const float*)d_in[12];
    const float* bhh  = (const float*)d_in[13];
    const float* Wfb  = (const float*)d_in[14];
    const float* bfb  = (const float*)d_in[15];
    const float* Wh0  = (const float*)d_in[16];
    const float* bh0  = (const float*)d_in[17];
    const float* Wc0  = (const float*)d_in[18];
    const float* bc0  = (const float*)d_in[19];
    const float* Wfc  = (const float*)d_in[20];
    const float* bfc  = (const float*)d_in[21];

    char* w = (char*)d_ws;
    size_t cur = 0;
    auto alloc = [&](size_t bytes)->char*{
        char* p = w + cur; cur = (cur + bytes + 255) & ~(size_t)255; return p;
    };
    int*   sind   = (int*)  alloc(256);
    int*   lens_s = (int*)  alloc(256);
    float* bsum   = (float*)alloc(4*DEC*4);
    float* mean   = (float*)alloc(BB*ENC*4);
    float* hpart  = (float*)alloc((size_t)8*64*1024*4);
    float* c      = (float*)alloc(BB*DEC*4);
    short* hh     = (short*)alloc((size_t)(TM1+1)*BB*DEC*2);
    float* dg     = (float*)alloc(BB*512*4);
    float* gateb  = (float*)alloc(BB*2048*4);
    short* inp    = (short*)alloc(BB*2560*2);
    short* embs   = (short*)alloc((size_t)BB*TM1*EMB*2);
    short* Wdp    = (short*)alloc((size_t)512*512*2);
    short* Web    = (short*)alloc((size_t)ENC*ATT*2);
    short* Bfb    = (short*)alloc((size_t)512*2048*2);
    short* Bg     = (short*)alloc((size_t)3072*2048*2);
    short* Wfcb   = (short*)alloc((size_t)512*VV*2);
    short* encat  = (short*)alloc((size_t)BB*LL*ATT*2);
    short* enc_s  = (short*)alloc((size_t)BB*LL*ENC*2);
    bool fast = (ws_size >= cur);
    int fastI = fast ? 1 : 0;

    float* out        = (float*)d_out;
    float* out_preds  = out;
    float* out_alphas = out + 32000000ull;
    float* out_cap    = out + 32313600ull;
    float* out_lens   = out + 32315264ull;

    // ---- prologue ----
    k_sort<<<1, 64, 0, stream>>>(clen, cap, bih, bhh, sind, lens_s, bsum,
                                 out_cap, out_lens);
    PrepArgs P;
    P.enc = enc; P.sind = sind; P.enc_s = enc_s;
    P.Wfc = Wfc; P.Wfcb = Wfcb;
    P.Wih = Wih; P.Whh = Whh; P.Bg = Bg;
    P.We = We; P.Web = Web;
    P.Wfb = Wfb; P.Bfb = Bfb;
    P.Wd = Wd; P.Wdp = Wdp;
    P.mean = mean;
    P.embW = embW; P.cap = cap; P.embs = embs;
    P.fast = fastI;
    P.blkoff = 0;
    k_prep<<<SEG0, 256, 0, stream>>>(P);          // enc conversion half
    PrepArgs P2 = P;
    P2.blkoff = SEG0;
    k_prep<<<SEG8 - SEG0, 256, 0, stream>>>(P2);  // weight-pack half

    k_h0part<<<dim3(16, 8), 256, 0, stream>>>(mean, Wh0, Wc0, hpart);
    k_h0fin<<<256, 256, 0, stream>>>(hpart, bh0, bc0, hh, c);

    if (fast)
        k_encatt_mfma<true ><<<dim3(196, 4), 256, 0, stream>>>(enc_s, sind, Web, be, encat);
    else
        k_encatt_mfma<false><<<dim3(196, 4), 256, 0, stream>>>(enc,   sind, Web, be, encat);

    // ---- decode loop: 3 dispatches per step ----
    for (int t = 0; t < TM1; t++){
        const short* h_in  = hh + (size_t)t*(BB*DEC);
        short*       h_out = hh + (size_t)(t+1)*(BB*DEC);
        k_hgemm<<<40, 256, 0, stream>>>(h_in, Wdp, Bfb, bd, bfb, dg, gateb);
        k_attnz<<<64, 512, 0, stream>>>(dg, encat, Wa, ba, embs, gateb, enc_s, enc,
                                        sind, lens_s, inp, out_alphas, t, fastI);
        k_glstm<<<32, 512, 0, stream>>>(inp, h_in, Bg, bsum, c, h_out);
    }
    // ---- batched pred GEMM over all steps ----
    k_predall<<<dim3(313, 5), 256, 0, stream>>>(hh, Wfcb, bfc, lens_s, out_preds);
}

// Round 11
// 1551.469 us; speedup vs baseline: 1.8635x; 1.1964x over previous
//
#include <hip/hip_runtime.h>
#include <hip/hip_bf16.h>

#define BB 64
#define LL 196
#define ENC 2048
#define DEC 512
#define EMB 512
#define ATT 512
#define VV 20000
#define TT 26
#define TM1 25

typedef __attribute__((ext_vector_type(8))) short bf16x8;
typedef __attribute__((ext_vector_type(4))) short bf16x4;
typedef __attribute__((ext_vector_type(4))) float f32x4;

#define MFMA16(a,b,c) __builtin_amdgcn_mfma_f32_16x16x32_bf16(a,b,c,0,0,0)

typedef const __attribute__((address_space(1))) void g_void;
typedef __attribute__((address_space(3))) void l_void;

// async global->LDS, 16B per lane; dest is wave-uniform base + lane*16
__device__ __forceinline__ void stage16(const void* g, void* l){
    __builtin_amdgcn_global_load_lds((g_void*)g, (l_void*)l, 16, 0, 0);
}

#define WAITV(N) asm volatile("s_waitcnt vmcnt(" #N ")" ::: "memory")
#define PHASE_SYNC() do { __builtin_amdgcn_s_barrier(); __builtin_amdgcn_sched_barrier(0); } while(0)

__device__ __forceinline__ float tanh_fast(float x){
    float ax = fabsf(x);
    float e  = __expf(-2.f*ax);
    float r  = (1.f - e)/(1.f + e);
    return x >= 0.f ? r : -r;
}
__device__ __forceinline__ float sigmoidf_(float x){
    return 1.f/(1.f + __expf(-x));
}
__device__ __forceinline__ short f2bf(float v){
    __hip_bfloat16 b = __float2bfloat16(v);
    return __builtin_bit_cast(short, b);
}
__device__ __forceinline__ float bf2f(short s){
    __hip_bfloat16 b = __builtin_bit_cast(__hip_bfloat16, s);
    return __bfloat162float(b);
}

// ---------------------------------------------------------------------------
// sort + cap/lens outputs + bias_sum
// ---------------------------------------------------------------------------
__global__ void k_sort(const int* __restrict__ clen, const int* __restrict__ cap,
                       const float* __restrict__ bih, const float* __restrict__ bhh,
                       int* __restrict__ sind, int* __restrict__ lens_s,
                       float* __restrict__ bsum,
                       float* __restrict__ out_cap, float* __restrict__ out_lens)
{
    int i = threadIdx.x;
    int li = clen[i];
    int r = 0;
    for (int j = 0; j < BB; j++){
        int lj = clen[j];
        r += (lj > li) || (lj == li && j < i);
    }
    sind[r] = i;
    lens_s[r] = li - 1;
    out_lens[r] = (float)(li - 1);
    for (int t = 0; t < TT; t++)
        out_cap[r*TT + t] = (float)cap[i*TT + t];
    for (int j = i; j < 4*DEC; j += BB)
        bsum[j] = bih[j] + bhh[j];
}

// ---------------------------------------------------------------------------
// k_prep: all packs / conversions / mean / embedding (segmented, 2 launches)
// ---------------------------------------------------------------------------
struct PrepArgs {
    const float* enc; const int* sind; short* enc_s;
    const float* Wfc; short* Wfcb;
    const float* Wih; const float* Whh; short* Bg;
    const float* We;  short* Web;
    const float* Wfb; short* Bfb;
    const float* Wd;  short* Wdp;
    float* mean;
    const float* embW; const int* cap; short* embs;
    int fast; int blkoff;
};

#define SEG0 12544               // cvt_enc
#define SEG1 (SEG0 + 5000)       // Wfc pack
#define SEG2 (SEG1 + 2560)       // Wih pack
#define SEG3 (SEG2 + 512)        // We pack
#define SEG4 (SEG3 + 512)        // Wfb pack
#define SEG5 (SEG4 + 512)        // Whh pack
#define SEG6 (SEG5 + 512)        // mean
#define SEG7 (SEG6 + 1600)       // emb
#define SEG8 (SEG7 + 128)        // Wd pack

__device__ __forceinline__ void pack_frag(int idx, const float* src, int ld,
                                          int K, int N, short* dst,
                                          int ktOff, int ntOff, int ntTot, bool NK)
{
    int ntCnt = N >> 4, ktCnt = K >> 5;
    int lane = idx & 63, rest = idx >> 6;
    if (rest >= ktCnt*ntCnt) return;
    int nt = rest % ntCnt, kt = rest / ntCnt;
    int k = kt*32 + (lane>>4)*8, n = nt*16 + (lane&15);
    bf16x8 v;
    #pragma unroll
    for (int j = 0; j < 8; j++){
        float f = NK ? src[(size_t)n*ld + k + j] : src[(size_t)(k+j)*ld + n];
        v[j] = f2bf(f);
    }
    *(bf16x8*)(dst + ((size_t)((kt+ktOff)*ntTot + (nt+ntOff))*64 + lane)*8) = v;
}

__launch_bounds__(256)
__global__ void k_prep(PrepArgs P)
{
    int blk = blockIdx.x + P.blkoff, tid = threadIdx.x;
    if (blk < SEG0){
        if (!P.fast) return;
        size_t idx = ((size_t)blk*256 + tid)*8;
        int r = (int)(idx / (LL*ENC));
        size_t rem = idx - (size_t)r*(LL*ENC);
        const float* s = P.enc + (size_t)P.sind[r]*(LL*ENC) + rem;
        bf16x8 v;
        float4 f0 = *(const float4*)s, f1 = *(const float4*)(s+4);
        v[0]=f2bf(f0.x); v[1]=f2bf(f0.y); v[2]=f2bf(f0.z); v[3]=f2bf(f0.w);
        v[4]=f2bf(f1.x); v[5]=f2bf(f1.y); v[6]=f2bf(f1.z); v[7]=f2bf(f1.w);
        *(bf16x8*)(P.enc_s + idx) = v;
    } else if (blk < SEG1){
        pack_frag((blk-SEG0)*256 + tid, P.Wfc, VV, 512, VV, P.Wfcb, 0, 0, 1250, false);
    } else if (blk < SEG2){
        pack_frag((blk-SEG1)*256 + tid, P.Wih, 2560, 2560, 2048, P.Bg, 0, 0, 128, true);
    } else if (blk < SEG3){
        pack_frag((blk-SEG2)*256 + tid, P.We, ATT, ENC, ATT, P.Web, 0, 0, 32, false);
    } else if (blk < SEG4){
        pack_frag((blk-SEG3)*256 + tid, P.Wfb, ENC, 512, 2048, P.Bfb, 0, 0, 128, false);
    } else if (blk < SEG5){
        pack_frag((blk-SEG4)*256 + tid, P.Whh, 512, 512, 2048, P.Bg, 80, 0, 128, true);
    } else if (blk < SEG6){
        int rel = blk - SEG5;           // 0..511
        int b = rel >> 3;
        int e = (rel & 7)*256 + tid;
        int sb = P.sind[b];
        const float* p = P.enc + ((size_t)sb*LL)*ENC + e;
        float s = 0.f;
        for (int l = 0; l < LL; l++) s += p[(size_t)l*ENC];
        P.mean[b*ENC + e] = s * (1.f/(float)LL);
    } else if (blk < SEG7){
        int rel = blk - SEG6;           // (b, t)
        int b = rel / 25, t = rel % 25;
        int token = P.cap[P.sind[b]*TT + t];
        const float* src = P.embW + (size_t)token*EMB + tid*2;
        unsigned u = (unsigned)(unsigned short)f2bf(src[0]) |
                     ((unsigned)(unsigned short)f2bf(src[1]) << 16);
        ((unsigned*)(P.embs + ((size_t)b*TM1 + t)*EMB))[tid] = u;
    } else if (blk < SEG8){
        pack_frag((blk-SEG7)*256 + tid, P.Wd, ATT, 512, 512, P.Wdp, 0, 0, 32, false);
    }
}

// ---------------------------------------------------------------------------
// h0/c0 split-K fp32
// ---------------------------------------------------------------------------
#define KT 32
__launch_bounds__(256)
__global__ void k_h0part(const float* __restrict__ A1, const float* __restrict__ B1,
                         const float* __restrict__ B2, float* __restrict__ hpart)
{
    __shared__ float As[KT][64];
    __shared__ float Bs[KT][64];
    const int tid = threadIdx.x;
    const int n0  = blockIdx.x*64;
    const int kq  = blockIdx.y;
    float acc[4][4] = {};
    const int lrow = tid >> 3, lcol = tid & 7;
    const int bn = (tid & 15)*4, bk = tid >> 4;
    const int bi0 = (tid >> 4)*4, nj0 = (tid & 15)*4;
    for (int k0 = kq*256; k0 < kq*256 + 256; k0 += KT){
        #pragma unroll
        for (int p = 0; p < 2; p++){
            int m = lrow + p*32;
            float4 v = *(const float4*)(A1 + (size_t)m*2048 + k0 + lcol*4);
            As[lcol*4+0][m] = v.x; As[lcol*4+1][m] = v.y;
            As[lcol*4+2][m] = v.z; As[lcol*4+3][m] = v.w;
        }
        {
            bool hi = (n0 >= 512);
            const float* B = hi ? B2 : B1;
            int ncol = n0 - (hi ? 512 : 0) + bn;
            #pragma unroll
            for (int p = 0; p < 2; p++){
                int k = bk + p*16;
                *(float4*)&Bs[k][bn] = *(const float4*)(B + (size_t)(k0+k)*512 + ncol);
            }
        }
        __syncthreads();
        #pragma unroll
        for (int k = 0; k < KT; k++){
            const float4 av = *(const float4*)&As[k][bi0];
            const float4 bv = *(const float4*)&Bs[k][nj0];
            acc[0][0] += av.x*bv.x; acc[0][1] += av.x*bv.y; acc[0][2] += av.x*bv.z; acc[0][3] += av.x*bv.w;
            acc[1][0] += av.y*bv.x; acc[1][1] += av.y*bv.y; acc[1][2] += av.y*bv.z; acc[1][3] += av.y*bv.w;
            acc[2][0] += av.z*bv.x; acc[2][1] += av.z*bv.y; acc[2][2] += av.z*bv.z; acc[2][3] += av.z*bv.w;
            acc[3][0] += av.w*bv.x; acc[3][1] += av.w*bv.y; acc[3][2] += av.w*bv.z; acc[3][3] += av.w*bv.w;
        }
        __syncthreads();
    }
    #pragma unroll
    for (int i = 0; i < 4; i++)
        #pragma unroll
        for (int j = 0; j < 4; j++){
            int b = bi0 + i, n = n0 + nj0 + j;
            hpart[((size_t)kq*64 + b)*1024 + n] = acc[i][j];
        }
}

__global__ void k_h0fin(const float* __restrict__ hpart, const float* __restrict__ bh0,
                        const float* __restrict__ bc0, short* __restrict__ h0,
                        float* __restrict__ c)
{
    int idx = blockIdx.x*256 + threadIdx.x;
    int b = idx >> 10, n = idx & 1023;
    float v = (n < 512) ? bh0[n] : bc0[n-512];
    for (int kq = 0; kq < 8; kq++) v += hpart[((size_t)kq*64 + b)*1024 + n];
    float r = tanh_fast(v);
    if (n < 512) h0[b*512 + n] = f2bf(r);
    else         c[b*512 + (n-512)] = r;
}

// ---------------------------------------------------------------------------
// enc_att MFMA: grid (196,4), 2 nt per wave
// ---------------------------------------------------------------------------
template<bool BF16SRC>
__launch_bounds__(256)
__global__ void k_encatt_mfma(const void* __restrict__ encp, const int* __restrict__ sind,
                              const short* __restrict__ Web, const float* __restrict__ be,
                              short* __restrict__ enc_att)
{
    __shared__ short As[64*32];
    int tid = threadIdx.x, wv = tid>>6, lane = tid&63;
    int hi = lane>>4, lo = lane&15;
    int m0 = blockIdx.x*64;
    int ntbase = blockIdx.y*8 + wv*2;
    int srow = tid>>2, schunk = tid&3;
    const short* gsrcB = nullptr; const float* gsrcF = nullptr;
    if (BF16SRC){
        gsrcB = (const short*)encp + (size_t)(m0+srow)*ENC + schunk*8;
    } else {
        int grow = m0 + srow;
        int b = grow/LL, l = grow - b*LL;
        gsrcF = (const float*)encp + ((size_t)sind[b]*LL + l)*ENC + schunk*8;
    }
    int sws = srow*32 + (schunk ^ ((srow>>1)&3))*8;
    f32x4 acc[2][4] = {};
    for (int kt = 0; kt < 64; kt++){
        bf16x8 v;
        if (BF16SRC){
            v = *(const bf16x8*)(gsrcB + kt*32);
        } else {
            float4 f0 = *(const float4*)(gsrcF + kt*32);
            float4 f1 = *(const float4*)(gsrcF + kt*32 + 4);
            v[0]=f2bf(f0.x); v[1]=f2bf(f0.y); v[2]=f2bf(f0.z); v[3]=f2bf(f0.w);
            v[4]=f2bf(f1.x); v[5]=f2bf(f1.y); v[6]=f2bf(f1.z); v[7]=f2bf(f1.w);
        }
        __syncthreads();
        *(bf16x8*)(As + sws) = v;
        __syncthreads();
        bf16x8 af[4];
        #pragma unroll
        for (int m = 0; m < 4; m++){
            int r = m*16 + lo;
            af[m] = *(const bf16x8*)(As + r*32 + (hi ^ ((r>>1)&3))*8);
        }
        #pragma unroll
        for (int n = 0; n < 2; n++){
            bf16x8 b = *(const bf16x8*)(Web + ((size_t)(kt*32 + ntbase + n)*64 + lane)*8);
            #pragma unroll
            for (int m = 0; m < 4; m++)
                acc[n][m] = MFMA16(af[m], b, acc[n][m]);
        }
    }
    #pragma unroll
    for (int n = 0; n < 2; n++)
        #pragma unroll
        for (int m = 0; m < 4; m++)
            #pragma unroll
            for (int j = 0; j < 4; j++){
                int row = m0 + m*16 + hi*4 + j;
                int col = (ntbase + n)*16 + lo;
                enc_att[(size_t)row*ATT + col] = f2bf(acc[n][m][j] + be[col]);
            }
}

// ---------------------------------------------------------------------------
// K1: dg (dec_att) + Wfb-gate. grid 40 x 256.
// 4 kt per phase: 4 phases. Ring depth 4 x 32KB = 128KB LDS.
// ---------------------------------------------------------------------------
__launch_bounds__(256)
__global__ void k_hgemm(const short* __restrict__ h_in, const short* __restrict__ Wdp,
                        const short* __restrict__ Bfb,
                        const float* __restrict__ bd, const float* __restrict__ bfb,
                        float* __restrict__ dg, float* __restrict__ gateb)
{
    __shared__ short ring[4*16384];
    int tid = threadIdx.x, wv = tid>>6, lane = tid&63;
    int hi = lane>>4, lo = lane&15;
    int gw = blockIdx.x*4 + wv;
    bool isdg = (gw < 32);
    int ntl  = isdg ? gw : gw - 32;
    int bstr = isdg ? 32 : 128;
    const short* Bp = isdg ? Wdp : Bfb;
    int srow = tid>>2;
    int swc  = (tid&3) ^ ((srow>>1)&3);
    int swz  = (hi ^ ((lo>>1)&3))*8;
    auto STG = [&](int q){
        short* buf = ring + q*16384;
        #pragma unroll
        for (int j = 0; j < 4; j++){
            int kt = 4*q + j;
            stage16(h_in + (size_t)srow*512 + kt*32 + swc*8,
                    buf + j*2048 + wv*512);
            stage16(Bp + ((size_t)(kt*bstr + ntl)*64 + lane)*8,
                    buf + 8192 + wv*2048 + j*512);
        }
    };
    STG(0); STG(1); STG(2);
    f32x4 acc[4] = {};
    auto CMP = [&](int pp){
        const short* buf = ring + pp*16384;
        #pragma unroll
        for (int j = 0; j < 4; j++){
            bf16x8 b = *(const bf16x8*)(buf + 8192 + wv*2048 + j*512 + lane*8);
            const short* Ab = buf + j*2048;
            #pragma unroll
            for (int m = 0; m < 4; m++){
                bf16x8 a = *(const bf16x8*)(Ab + (m*16 + lo)*32 + swz);
                acc[m] = MFMA16(a, b, acc[m]);
            }
        }
    };
    WAITV(16); PHASE_SYNC(); STG(3); CMP(0);
    WAITV(16); PHASE_SYNC(); CMP(1);
    WAITV(8);  PHASE_SYNC(); CMP(2);
    WAITV(0);  PHASE_SYNC(); CMP(3);
    int col = ntl*16 + lo;
    if (isdg){
        #pragma unroll
        for (int m = 0; m < 4; m++)
            #pragma unroll
            for (int j = 0; j < 4; j++)
                dg[(m*16 + hi*4 + j)*512 + col] = acc[m][j] + bd[col];
    } else {
        #pragma unroll
        for (int m = 0; m < 4; m++)
            #pragma unroll
            for (int j = 0; j < 4; j++)
                gateb[(m*16 + hi*4 + j)*2048 + col] = sigmoidf_(acc[m][j] + bfb[col]);
    }
}

// ---------------------------------------------------------------------------
// K2: scores -> softmax -> z -> gated inp. grid (64, 4): blockIdx.x = b,
// blockIdx.y = qs (512-col z slice). Scores/softmax duplicated across qs
// (cheap: 200KB encat + 100K tanh) so z uses 256 blocks = full machine.
// z: 16-way l-split (12-iter chains) over 32 16-col groups per slice.
// ---------------------------------------------------------------------------
__launch_bounds__(512)
__global__ void k_attnz(const float* __restrict__ dg, const short* __restrict__ encat,
                        const float* __restrict__ Wa, const float* __restrict__ ba,
                        const short* __restrict__ embs, const float* __restrict__ gateb,
                        const short* __restrict__ enc_s, const float* __restrict__ enc,
                        const int* __restrict__ sind, const int* __restrict__ lens_s,
                        short* __restrict__ inp, float* __restrict__ out_alphas,
                        int t, int fast)
{
    __shared__ float da[512];
    __shared__ float was[512];
    __shared__ float sc[200];
    __shared__ float red[16];
    __shared__ float al[200];
    __shared__ float zpart[16*512];
    int b = blockIdx.x, qs = blockIdx.y, tid = threadIdx.x;
    int lane = tid & 63, wv = tid >> 6;
    da[tid] = dg[b*512 + tid];
    was[tid] = Wa[tid];
    __syncthreads();
    float ba_v = ba[0];
    for (int l = wv; l < LL; l += 8){
        const short* ea = encat + ((size_t)b*LL + l)*ATT;
        float s = 0.f;
        #pragma unroll
        for (int q = 0; q < 8; q++){
            int a = lane + q*64;
            s += tanh_fast(bf2f(ea[a]) + da[a]) * was[a];
        }
        #pragma unroll
        for (int off = 32; off; off >>= 1) s += __shfl_xor(s, off);
        if (lane == 0) sc[l] = s + ba_v;
    }
    __syncthreads();
    float v = -1e30f, e = 0.f;
    if (tid < 256){
        v = (tid < LL) ? sc[tid] : -1e30f;
        float mx = v;
        #pragma unroll
        for (int off = 32; off; off >>= 1) mx = fmaxf(mx, __shfl_xor(mx, off));
        if (lane == 0) red[wv] = mx;
    }
    if (qs == 0 && tid < 256){
        const unsigned* s32 = (const unsigned*)(embs + ((size_t)b*TM1 + t)*EMB);
        ((unsigned*)(inp + (size_t)b*2560))[tid] = s32[tid];
    }
    __syncthreads();
    float mxa = fmaxf(fmaxf(red[0], red[1]), fmaxf(red[2], red[3]));
    if (tid < 256){
        e = (tid < LL) ? __expf(v - mxa) : 0.f;
        float sm = e;
        #pragma unroll
        for (int off = 32; off; off >>= 1) sm += __shfl_xor(sm, off);
        if (lane == 0) red[8 + wv] = sm;
    }
    __syncthreads();
    float tot = red[8] + red[9] + red[10] + red[11];
    if (tid < LL){
        float alv = e / tot;
        al[tid] = alv;
        if (qs == 0){
            float m = (t < lens_s[b]) ? 1.f : 0.f;
            out_alphas[((size_t)b*TM1 + t)*LL + tid] = alv * m;
        }
    }
    __syncthreads();
    // z: thread (ls, cs): ls = l-slice 0..15 (12-13 iters), cs = 16-col group
    // within this block's 512-col slice [qs*512, qs*512+512)
    {
        int ls = tid >> 5;          // 0..15
        int cs = tid & 31;          // 0..31
        int c0 = qs*512 + cs*16;
        float a16[16] = {};
        if (fast){
            const short* base = enc_s + ((size_t)b*LL)*ENC + c0;
            for (int l = ls; l < LL; l += 16){
                float av = al[l];
                const short* r = base + (size_t)l*ENC;
                bf16x8 v0 = *(const bf16x8*)(r);
                bf16x8 v1 = *(const bf16x8*)(r + 8);
                #pragma unroll
                for (int j = 0; j < 8; j++){
                    a16[j]     += av*bf2f(v0[j]);
                    a16[8 + j] += av*bf2f(v1[j]);
                }
            }
        } else {
            const float* base = enc + ((size_t)sind[b]*LL)*ENC + c0;
            for (int l = ls; l < LL; l += 16){
                float av = al[l];
                const float* r = base + (size_t)l*ENC;
                float4 f0 = *(const float4*)(r),     f1 = *(const float4*)(r+4);
                float4 f2 = *(const float4*)(r + 8), f3 = *(const float4*)(r+12);
                a16[0]+=av*f0.x; a16[1]+=av*f0.y; a16[2]+=av*f0.z; a16[3]+=av*f0.w;
                a16[4]+=av*f1.x; a16[5]+=av*f1.y; a16[6]+=av*f1.z; a16[7]+=av*f1.w;
                a16[8]+=av*f2.x; a16[9]+=av*f2.y; a16[10]+=av*f2.z; a16[11]+=av*f2.w;
                a16[12]+=av*f3.x; a16[13]+=av*f3.y; a16[14]+=av*f3.z; a16[15]+=av*f3.w;
            }
        }
        // rotated-order scalar writes: instruction jj writes slot (jj+cs)&15
        float* zp = zpart + ls*512 + cs*16;
        #pragma unroll
        for (int jj = 0; jj < 16; jj++){
            int slot = (jj + cs) & 15;
            zp[slot] = a16[slot];
        }
    }
    __syncthreads();
    if (tid < 128){
        int c = tid*4;              // col within slice
        int cabs = qs*512 + c;
        const float* gt = gateb + (size_t)b*2048 + cabs;
        bf16x4 o;
        #pragma unroll
        for (int j = 0; j < 4; j++){
            float s = 0.f;
            #pragma unroll
            for (int ls = 0; ls < 16; ls++)
                s += zpart[ls*512 + c + j];
            o[j] = f2bf(gt[j] * s);
        }
        *(bf16x4*)(inp + (size_t)b*2560 + 512 + cabs) = o;
    }
}

// ---------------------------------------------------------------------------
// K3: g GEMM (split-K=2) + LSTM. 32 blocks x 512 thr.
// 3 kt per phase: 16 phases. Ring DEPTH 3 x 48KB = 144KB LDS.
// ---------------------------------------------------------------------------
__launch_bounds__(512)
__global__ void k_glstm(const short* __restrict__ inp, const short* __restrict__ h_in,
                        const short* __restrict__ Bg, const float* __restrict__ bsum,
                        float* __restrict__ c, short* __restrict__ h_out)
{
    __shared__ short ring[3*24576];           // 144KB; gs unioned in after loop
    float* gs = (float*)ring;
    int tid = threadIdx.x, wv = tid>>6, lane = tid&63;
    int hi = lane>>4, lo = lane&15;
    int gate = wv & 3, khalf = wv >> 2;
    int j16 = blockIdx.x;
    int nt = gate*32 + j16;
    int sl   = tid >> 8;             // A-slice group (khalf) this thread stages
    int st   = tid & 255;
    int srow = st >> 2;
    int swc  = (st&3) ^ ((srow>>1)&3);
    int swz  = (hi ^ ((lo>>1)&3))*8;
    auto STG = [&](int q){
        short* buf = ring + (q%3)*24576;
        #pragma unroll
        for (int j = 0; j < 3; j++){
            int kt = sl*48 + 3*q + j;
            const short* src;
            if (kt < 80) src = inp  + (size_t)srow*2560 + kt*32 + swc*8;
            else         src = h_in + (size_t)srow*512  + (kt-80)*32 + swc*8;
            stage16(src, buf + (sl*3 + j)*2048 + (wv&3)*512);
            int ktw = khalf*48 + 3*q + j;
            stage16(Bg + ((size_t)(ktw*128 + nt)*64 + lane)*8,
                    buf + 12288 + wv*1536 + j*512);
        }
    };
    STG(0); STG(1);
    f32x4 acc[4] = {};
    auto CMP = [&](int pp){
        const short* buf = ring + (pp%3)*24576;
        #pragma unroll
        for (int j = 0; j < 3; j++){
            bf16x8 b = *(const bf16x8*)(buf + 12288 + wv*1536 + j*512 + lane*8);
            const short* Ab = buf + (khalf*3 + j)*2048;
            #pragma unroll
            for (int m = 0; m < 4; m++){
                bf16x8 a = *(const bf16x8*)(Ab + (m*16 + lo)*32 + swz);
                acc[m] = MFMA16(a, b, acc[m]);
            }
        }
    };
    for (int pp = 0; pp < 14; pp++){
        WAITV(6); PHASE_SYNC();
        STG(pp + 2);
        CMP(pp);
    }
    WAITV(6); PHASE_SYNC(); CMP(14);
    WAITV(0); PHASE_SYNC(); CMP(15);
    __syncthreads();                 // all ring reads done before gs overwrite
    #pragma unroll
    for (int m = 0; m < 4; m++)
        #pragma unroll
        for (int j = 0; j < 4; j++)
            gs[wv*1088 + (m*16 + hi*4 + j)*17 + lo] = acc[m][j];
    __syncthreads();
    #pragma unroll
    for (int rep = 0; rep < 2; rep++){
        int idx = rep*512 + tid;
        int row = idx >> 4, cl = idx & 15;
        int col = j16*16 + cl;
        float s0 = gs[0*1088 + row*17 + cl] + gs[4*1088 + row*17 + cl] + bsum[col];
        float s1 = gs[1*1088 + row*17 + cl] + gs[5*1088 + row*17 + cl] + bsum[512 + col];
        float s2 = gs[2*1088 + row*17 + cl] + gs[6*1088 + row*17 + cl] + bsum[1024 + col];
        float s3 = gs[3*1088 + row*17 + cl] + gs[7*1088 + row*17 + cl] + bsum[1536 + col];
        int ci = row*512 + col;
        float cn = sigmoidf_(s1)*c[ci] + sigmoidf_(s0)*tanh_fast(s2);
        c[ci] = cn;
        h_out[ci] = f2bf(sigmoidf_(s3)*tanh_fast(cn));
    }
}

// ---------------------------------------------------------------------------
// K4: batched pred GEMM over all 25 steps. grid (313,5) — measured optimum
// of the mt-split knob (5: 72us/58MB fetch; 13: 95us/138MB; 25: 371us).
// ---------------------------------------------------------------------------
__launch_bounds__(256)
__global__ void k_predall(const short* __restrict__ hh, const short* __restrict__ Wfcb,
                          const float* __restrict__ bfc, const int* __restrict__ lens_s,
                          float* __restrict__ out_preds)
{
    __shared__ short ring[4*2048];
    int tid = threadIdx.x, wv = tid>>6, lane = tid&63;
    int hi = lane>>4, lo = lane&15;
    int nt = blockIdx.x*4 + wv;
    if (nt > 1249) nt = 1249;        // duplicate work; identical values stored
    int mt0 = blockIdx.y*5;
    bf16x8 breg[16];
    #pragma unroll
    for (int kt = 0; kt < 16; kt++)
        breg[kt] = *(const bf16x8*)(Wfcb + ((size_t)(kt*1250 + nt)*64 + lane)*8);
    int col = nt*16 + lo;
    float bv = bfc[col];
    int lv[16];
    #pragma unroll
    for (int m = 0; m < 4; m++)
        #pragma unroll
        for (int j = 0; j < 4; j++)
            lv[m*4 + j] = lens_s[m*16 + hi*4 + j];

    int srow = tid>>2;
    int swc  = (tid&3) ^ ((srow>>1)&3);
    int swz  = (hi ^ ((lo>>1)&3))*8;
    const short* hh0 = hh + (size_t)(mt0 + 1)*(BB*DEC);
    auto STG = [&](int q){
        const short* src = hh0 + (size_t)(q>>4)*(BB*DEC) + (size_t)srow*512
                         + (q&15)*32 + swc*8;
        stage16(src, ring + (q&3)*2048 + wv*512);
    };
    STG(0); STG(1); STG(2);

    auto CMP = [&](f32x4* acc, int kt, int pp){
        const short* base = ring + (pp&3)*2048;
        #pragma unroll
        for (int m = 0; m < 4; m++){
            bf16x8 a = *(const bf16x8*)(base + (m*16 + lo)*32 + swz);
            acc[m] = MFMA16(a, breg[kt], acc[m]);
        }
    };
    auto STORE = [&](f32x4* acc, int mta){
        #pragma unroll
        for (int m = 0; m < 4; m++)
            #pragma unroll
            for (int j = 0; j < 4; j++){
                int row = m*16 + hi*4 + j;
                float mk = (mta < lv[m*4 + j]) ? 1.f : 0.f;
                out_preds[((size_t)row*TM1 + mta)*VV + col] = mk*(acc[m][j] + bv);
            }
    };

    for (int mt = 0; mt < 4; mt++){
        f32x4 acc[4] = {};
        #pragma unroll
        for (int kt = 0; kt < 16; kt++){
            int pp = mt*16 + kt;
            WAITV(2); PHASE_SYNC();
            STG(pp + 3);
            CMP(acc, kt, pp);
        }
        STORE(acc, mt0 + mt);
    }
    {   // mt = 4 with counted tail drain
        f32x4 acc[4] = {};
        #pragma unroll
        for (int kt = 0; kt < 13; kt++){
            int pp = 64 + kt;
            WAITV(2); PHASE_SYNC();
            if (pp < 77) STG(pp + 3);
            CMP(acc, kt, pp);
        }
        WAITV(2); PHASE_SYNC(); CMP(acc, 13, 77);
        WAITV(1); PHASE_SYNC(); CMP(acc, 14, 78);
        WAITV(0); PHASE_SYNC(); CMP(acc, 15, 79);
        STORE(acc, mt0 + 4);
    }
}

// ---------------------------------------------------------------------------
extern "C" void kernel_launch(void* const* d_in, const int* in_sizes, int n_in,
                              void* d_out, int out_size, void* d_ws, size_t ws_size,
                              hipStream_t stream)
{
    const float* enc  = (const float*)d_in[0];
    const int*   cap  = (const int*)  d_in[1];
    const int*   clen = (const int*)  d_in[2];
    const float* embW = (const float*)d_in[3];
    const float* We   = (const float*)d_in[4];
    const float* be   = (const float*)d_in[5];
    const float* Wd   = (const float*)d_in[6];
    const float* bd   = (const float*)d_in[7];
    const float* Wa   = (const float*)d_in[8];
    const float* ba   = (const float*)d_in[9];
    const float* Wih  = (const float*)d_in[10];
    const float* bih  = (const float*)d_in[11];
    const float* Whh  = (const float*)d_in[12];
    const float* bhh  = (const float*)d_in[13];
    const float* Wfb  = (const float*)d_in[14];
    const float* bfb  = (const float*)d_in[15];
    const float* Wh0  = (const float*)d_in[16];
    const float* bh0  = (const float*)d_in[17];
    const float* Wc0  = (const float*)d_in[18];
    const float* bc0  = (const float*)d_in[19];
    const float* Wfc  = (const float*)d_in[20];
    const float* bfc  = (const float*)d_in[21];

    char* w = (char*)d_ws;
    size_t cur = 0;
    auto alloc = [&](size_t bytes)->char*{
        char* p = w + cur; cur = (cur + bytes + 255) & ~(size_t)255; return p;
    };
    int*   sind   = (int*)  alloc(256);
    int*   lens_s = (int*)  alloc(256);
    float* bsum   = (float*)alloc(4*DEC*4);
    float* mean   = (float*)alloc(BB*ENC*4);
    float* hpart  = (float*)alloc((size_t)8*64*1024*4);
    float* c      = (float*)alloc(BB*DEC*4);
    short* hh     = (short*)alloc((size_t)(TM1+1)*BB*DEC*2);
    float* dg     = (float*)alloc(BB*512*4);
    float* gateb  = (float*)alloc(BB*2048*4);
    short* inp    = (short*)alloc(BB*2560*2);
    short* embs   = (short*)alloc((size_t)BB*TM1*EMB*2);
    short* Wdp    = (short*)alloc((size_t)512*512*2);
    short* Web    = (short*)alloc((size_t)ENC*ATT*2);
    short* Bfb    = (short*)alloc((size_t)512*2048*2);
    short* Bg     = (short*)alloc((size_t)3072*2048*2);
    short* Wfcb   = (short*)alloc((size_t)512*VV*2);
    short* encat  = (short*)alloc((size_t)BB*LL*ATT*2);
    short* enc_s  = (short*)alloc((size_t)BB*LL*ENC*2);
    bool fast = (ws_size >= cur);
    int fastI = fast ? 1 : 0;

    float* out        = (float*)d_out;
    float* out_preds  = out;
    float* out_alphas = out + 32000000ull;
    float* out_cap    = out + 32313600ull;
    float* out_lens   = out + 32315264ull;

    // ---- prologue ----
    k_sort<<<1, 64, 0, stream>>>(clen, cap, bih, bhh, sind, lens_s, bsum,
                                 out_cap, out_lens);
    PrepArgs P;
    P.enc = enc; P.sind = sind; P.enc_s = enc_s;
    P.Wfc = Wfc; P.Wfcb = Wfcb;
    P.Wih = Wih; P.Whh = Whh; P.Bg = Bg;
    P.We = We; P.Web = Web;
    P.Wfb = Wfb; P.Bfb = Bfb;
    P.Wd = Wd; P.Wdp = Wdp;
    P.mean = mean;
    P.embW = embW; P.cap = cap; P.embs = embs;
    P.fast = fastI;
    P.blkoff = 0;
    k_prep<<<SEG0, 256, 0, stream>>>(P);          // enc conversion half
    PrepArgs P2 = P;
    P2.blkoff = SEG0;
    k_prep<<<SEG8 - SEG0, 256, 0, stream>>>(P2);  // weight-pack half

    k_h0part<<<dim3(16, 8), 256, 0, stream>>>(mean, Wh0, Wc0, hpart);
    k_h0fin<<<256, 256, 0, stream>>>(hpart, bh0, bc0, hh, c);

    if (fast)
        k_encatt_mfma<true ><<<dim3(196, 4), 256, 0, stream>>>(enc_s, sind, Web, be, encat);
    else
        k_encatt_mfma<false><<<dim3(196, 4), 256, 0, stream>>>(enc,   sind, Web, be, encat);

    // ---- decode loop: 3 dispatches per step ----
    for (int t = 0; t < TM1; t++){
        const short* h_in  = hh + (size_t)t*(BB*DEC);
        short*       h_out = hh + (size_t)(t+1)*(BB*DEC);
        k_hgemm<<<40, 256, 0, stream>>>(h_in, Wdp, Bfb, bd, bfb, dg, gateb);
        k_attnz<<<dim3(64, 4), 512, 0, stream>>>(dg, encat, Wa, ba, embs, gateb,
                                                 enc_s, enc, sind, lens_s,
                                                 inp, out_alphas, t, fastI);
        k_glstm<<<32, 512, 0, stream>>>(inp, h_in, Bg, bsum, c, h_out);
    }
    // ---- batched pred GEMM over all steps ----
    k_predall<<<dim3(313, 5), 256, 0, stream>>>(hh, Wfcb, bfc, lens_s, out_preds);
}